// Round 1
// baseline (190.713 us; speedup 1.0000x reference)
//
#include <hip/hip_runtime.h>
#include <hip/hip_bf16.h>
#include <stdint.h>

#define D_MODEL 1024
#define NHEADS  16
#define DKH     64
#define BATCH   2
#define SEQ     2048
#define MTOT    (BATCH*SEQ)   // 4096

typedef __attribute__((ext_vector_type(8)))  short bf16x8;   // 8 bf16 = 4 VGPRs
typedef __attribute__((ext_vector_type(4)))  float f32x4;
typedef __attribute__((ext_vector_type(16))) float f32x16;
typedef __attribute__((ext_vector_type(4)))  unsigned int u32x4;

__device__ inline unsigned short f2bf(float f) {
    __hip_bfloat16 h = __float2bfloat16(f);
    return *reinterpret_cast<unsigned short*>(&h);
}
__device__ inline unsigned int pack2bf(float a, float b) {   // low=a, high=b (RNE)
    __hip_bfloat162 h = __float22bfloat162_rn(float2{a, b});
    return *reinterpret_cast<unsigned int*>(&h);
}

// async global->LDS, 16B per lane; LDS dest = wave-uniform base + lane*16 (m97/m104)
__device__ inline void gl2lds16(const unsigned short* g, unsigned short* l) {
    __builtin_amdgcn_global_load_lds(
        (const __attribute__((address_space(1))) void*)g,
        (__attribute__((address_space(3))) void*)l,
        16, 0, 0);
}

// One-shot fp32 -> bf16 conversion of x and the 4 weight matrices.
__global__ __launch_bounds__(256) void cvt_all(
    const float* __restrict__ x,  const float* __restrict__ wq,
    const float* __restrict__ wk, const float* __restrict__ wv,
    const float* __restrict__ wo,
    unsigned short* __restrict__ xb,  unsigned short* __restrict__ wqb,
    unsigned short* __restrict__ wkb, unsigned short* __restrict__ wvb,
    unsigned short* __restrict__ wob)
{
    int bid = blockIdx.x;
    const float* s; unsigned short* d; size_t base;
    if (bid < 2048) { s = x; d = xb; base = (size_t)bid * 2048; }
    else {
        int w  = (bid - 2048) >> 9;
        int wb = (bid - 2048) & 511;
        s = (w == 0) ? wq : (w == 1) ? wk : (w == 2) ? wv : wo;
        d = (w == 0) ? wqb : (w == 1) ? wkb : (w == 2) ? wvb : wob;
        base = (size_t)wb * 2048;
    }
    size_t i = base + (size_t)threadIdx.x * 8;
    float4 a = *(const float4*)(s + i);
    float4 b = *(const float4*)(s + i + 4);
    unsigned short t8[8] = {f2bf(a.x), f2bf(a.y), f2bf(a.z), f2bf(a.w),
                            f2bf(b.x), f2bf(b.y), f2bf(b.z), f2bf(b.w)};
    *(uint4*)(d + i) = *(uint4*)t8;
}

// C[M,N] = scale * A[M,K] @ W[N,K]^T ; bf16 in, fp32 accum, C bf16 or fp32.
// BK=64 as two m97-style BK=32 sub-tiles (unpadded 128x32, global_load_lds w=16).
// VSWAP: blockIdx.z==2 computes C = W2 @ A^T (emits V^T directly).
template<bool CF32, bool VSWAP>
__global__ __launch_bounds__(256) void gemm_bt(
    const unsigned short* __restrict__ A,
    const unsigned short* __restrict__ W0,
    const unsigned short* __restrict__ W1,
    const unsigned short* __restrict__ W2,
    void* __restrict__ C0, void* __restrict__ C1, void* __restrict__ C2,
    int M, int N, int K, float scale0)
{
    const bool sw = VSWAP && (blockIdx.z == 2);
    const unsigned short* Aeff = sw ? W2 : A;
    const unsigned short* Weff = (blockIdx.z == 0) ? W0 : (blockIdx.z == 1 ? W1 : (sw ? A : W2));
    void* C = (blockIdx.z == 0) ? C0 : (blockIdx.z == 1 ? C1 : C2);
    const int Neff = sw ? M : N;
    const float scl = (blockIdx.z == 0) ? scale0 : 1.0f;
    const int m0 = (sw ? blockIdx.y : blockIdx.x) * 128;
    const int n0 = (sw ? blockIdx.x : blockIdx.y) * 128;

    __shared__ __align__(16) unsigned short As[2][128 * 32];
    __shared__ __align__(16) unsigned short Bs[2][128 * 32];

    const int t    = threadIdx.x;
    const int wave = t >> 6, lane = t & 63;
    const int quad = lane >> 4, l16 = lane & 15;
    const int wm   = (wave >> 1) * 64, wn = (wave & 1) * 64;

    const int srow = lane >> 2;
    const int schk = (lane & 3) * 8;   // shorts
    const unsigned short* Ag = Aeff + (size_t)(m0 + wave * 32 + srow) * K + schk;
    const unsigned short* Wg = Weff + (size_t)(n0 + wave * 32 + srow) * K + schk;
    const size_t rstep = (size_t)16 * K;
    unsigned short* AsB0 = &As[0][0] + wave * 1024;
    unsigned short* BsB0 = &Bs[0][0] + wave * 1024;

    f32x4 acc[4][4] = {};

    for (int k0 = 0; k0 < K; k0 += 64) {
        __syncthreads();
        #pragma unroll
        for (int s = 0; s < 2; ++s) {
            gl2lds16(Ag + k0 + s * 32,         AsB0 + s * 4096);
            gl2lds16(Ag + k0 + s * 32 + rstep, AsB0 + s * 4096 + 512);
            gl2lds16(Wg + k0 + s * 32,         BsB0 + s * 4096);
            gl2lds16(Wg + k0 + s * 32 + rstep, BsB0 + s * 4096 + 512);
        }
        __syncthreads();

        #pragma unroll
        for (int s = 0; s < 2; ++s) {
            bf16x8 afr[4], bfr[4];
            #pragma unroll
            for (int i = 0; i < 4; ++i) {
                afr[i] = *(const bf16x8*)(&As[s][0] + (wm + i * 16 + l16) * 32 + quad * 8);
                bfr[i] = *(const bf16x8*)(&Bs[s][0] + (wn + i * 16 + l16) * 32 + quad * 8);
            }
            #pragma unroll
            for (int i = 0; i < 4; ++i)
                #pragma unroll
                for (int j = 0; j < 4; ++j)
                    acc[i][j] = __builtin_amdgcn_mfma_f32_16x16x32_bf16(afr[i], bfr[j], acc[i][j], 0, 0, 0);
        }
    }

    #pragma unroll
    for (int i = 0; i < 4; ++i)
        #pragma unroll
        for (int j = 0; j < 4; ++j)
            #pragma unroll
            for (int r = 0; r < 4; ++r) {
                int row = m0 + wm + i * 16 + quad * 4 + r;
                int col = n0 + wn + j * 16 + l16;
                float v = acc[i][j][r] * scl;
                if (CF32) ((float*)C)[(size_t)row * Neff + col] = v;
                else      ((unsigned short*)C)[(size_t)row * Neff + col] = f2bf(v);
            }
}

// Flash causal attention, fixed-m softmax, 32x32x16 MFMA.
// RESTRUCTURED vs prev round: 128-q blocks (was 64). Each of the 4 waves owns
// its own 32 q-rows and walks the FULL key range (no split-key waves, no merge
// epilogue). Every staged 64-key K/V tile now serves 128 q-rows instead of 64:
// barriers, ds_write staging, and global K/V tile traffic are HALVED per q at
// identical MFMA/softmax work per (q,key). Per-wave causal skip is uniform
// (gk>gq) so barrier alignment is preserved.
// grid (32=b*h, 16 q-tiles, paired y<8?y:23-y so 2 resident blocks/CU sum to
// constant work), block 256.
__global__ __launch_bounds__(256, 4) void attn_kernel(
    const unsigned short* __restrict__ Qm,
    const unsigned short* __restrict__ Km,
    const unsigned short* __restrict__ VtG,
    unsigned short* __restrict__ Om)
{
    const int bh = blockIdx.x;
    const int y  = blockIdx.y;
    const int qt = (y < 8) ? y : 23 - y;       // pairs (y, y+8): work (qt+1) sums to 17
    const int h  = bh & 15;
    const int b  = bh >> 4;
    const int t    = threadIdx.x;
    const int wave = t >> 6, lane = t & 63;
    const int l31  = lane & 31, h32 = lane >> 5;

    __shared__ __align__(16) unsigned short S[2][64 * 72];
    unsigned short* Ks = &S[0][0];            // K tile [key][dk], stride 72
    unsigned short* Vt = &S[1][0];            // V^T tile [dk][key], stride 72

    const size_t base = (size_t)b * SEQ * D_MODEL + (size_t)h * DKH;
    const unsigned short* Qh = Qm + base;
    const unsigned short* Kh = Km + base;
    const unsigned short* Vh = VtG + (size_t)h * DKH * MTOT + (size_t)b * SEQ;  // [dk][m]

    const int q0 = qt * 128;
    const int gq = qt * 4 + wave;             // this wave's 32-q group index

    // Q B-frags (Q pre-scaled by log2e/8): B[n=q=l31][k=h32*8+j], 4 k-steps = dk 64
    const int qrow = q0 + wave * 32 + l31;
    bf16x8 qf[4];
    #pragma unroll
    for (int ks = 0; ks < 4; ++ks)
        qf[ks] = *(const bf16x8*)(Qh + (size_t)qrow * D_MODEL + ks * 16 + h32 * 8);

    f32x16 accOT[2] = {};   // O^T: col=l31=q, row=(reg&3)+8*(reg>>2)+4*h32=dk (+32*db)
    float  l_s = 0.f;       // row-sum for q=l31 over this lane's key slots

    const int srow = t >> 2, scol = (t & 3) * 16;
    const int ntiles = 2 * qt + 2;            // 64-key tiles covering q0+127

    // prefetch K/V tile 0 into regs
    uint4 kr0, kr1, vr0, vr1;
    {
        const unsigned short* ksrc = Kh + (size_t)srow * D_MODEL + scol;
        kr0 = *(const uint4*)ksrc; kr1 = *(const uint4*)(ksrc + 8);
        const unsigned short* vsrc = Vh + (size_t)srow * MTOT + scol;
        vr0 = *(const uint4*)vsrc; vr1 = *(const uint4*)(vsrc + 8);
    }

    for (int kt = 0; kt < ntiles; ++kt) {
        __syncthreads();   // prior iter's frag reads done
        *(uint4*)(Ks + srow * 72 + scol)     = kr0;
        *(uint4*)(Ks + srow * 72 + scol + 8) = kr1;
        *(uint4*)(Vt + srow * 72 + scol)     = vr0;
        *(uint4*)(Vt + srow * 72 + scol + 8) = vr1;
        __syncthreads();

        if (kt + 1 < ntiles) {   // prefetch next tile; overlaps compute below
            const unsigned short* ksrc = Kh + (size_t)((kt + 1) * 64 + srow) * D_MODEL + scol;
            kr0 = *(const uint4*)ksrc; kr1 = *(const uint4*)(ksrc + 8);
            const unsigned short* vsrc = Vh + (size_t)srow * MTOT + (kt + 1) * 64 + scol;
            vr0 = *(const uint4*)vsrc; vr1 = *(const uint4*)(vsrc + 8);
        }

        #pragma unroll
        for (int kh = 0; kh < 2; ++kh) {
            const int gk = kt * 2 + kh;       // 32-key group index
            if (gk > gq) continue;            // wave-uniform causal skip
            const int kb = kh * 32;

            // S^T = K Q^T : A = K rows
            f32x16 sT = {};
            #pragma unroll
            for (int ks = 0; ks < 4; ++ks) {
                bf16x8 kf = *(const bf16x8*)(Ks + (kb + l31) * 72 + ks * 16 + h32 * 8);
                sT = __builtin_amdgcn_mfma_f32_32x32x16_bf16(kf, qf[ks], sT, 0, 0, 0);
            }

            // p = exp2(s); diagonal group: keep key(rloc) <= q(l31)
            const bool maskq = (gk == gq);
            float pvv[16];
            #pragma unroll
            for (int reg = 0; reg < 16; ++reg) {
                const int rloc = (reg & 3) + 8 * (reg >> 2) + 4 * h32;   // key_local
                float v = sT[reg];
                if (maskq) v = (rloc <= l31) ? v : -1e30f;
                float p = exp2f(v);
                l_s += p;
                pvv[reg] = p;
            }
            // pack pairs (consecutive regs = consecutive keys) and half-wave exchange
            unsigned int pk[8], pr[8];
            #pragma unroll
            for (int i = 0; i < 8; ++i) pk[i] = pack2bf(pvv[2 * i], pvv[2 * i + 1]);
            #pragma unroll
            for (int i = 0; i < 8; ++i) pr[i] = __shfl_xor(pk[i], 32, 64);

            // O^T += V^T P^T : A = V^T rows, B = P^T in regs
            #pragma unroll
            for (int ks2 = 0; ks2 < 2; ++ks2) {
                union { u32x4 u; bf16x8 b; } pf;
                pf.u[0] = h32 ? pr[4 * ks2 + 2] : pk[4 * ks2 + 0];
                pf.u[1] = h32 ? pr[4 * ks2 + 3] : pk[4 * ks2 + 1];
                pf.u[2] = h32 ? pk[4 * ks2 + 2] : pr[4 * ks2 + 0];
                pf.u[3] = h32 ? pk[4 * ks2 + 3] : pr[4 * ks2 + 1];
                #pragma unroll
                for (int db = 0; db < 2; ++db) {
                    bf16x8 vf = *(const bf16x8*)(Vt + (db * 32 + l31) * 72 + kb + ks2 * 16 + h32 * 8);
                    accOT[db] = __builtin_amdgcn_mfma_f32_32x32x16_bf16(vf, pf.b, accOT[db], 0, 0, 0);
                }
            }
        }
    }

    // combine the two h32 key-halves of the same q, then normalize
    l_s += __shfl_xor(l_s, 32, 64);
    const float inv = 1.f / l_s;

    // ---- transpose O^T -> [q][dk] bf16 tile across the dead Ks+Vt, store ----
    __syncthreads();                          // all frag reads done; S reusable
    unsigned short* Ot = &S[0][0];            // flat [128][68] u16 = 17408B <= 18432B
    {
        const int row = wave * 32 + l31;
        #pragma unroll
        for (int db = 0; db < 2; ++db)
            #pragma unroll
            for (int c = 0; c < 4; ++c) {
                // dk pairs: (8c+4*h32, +1) and (+2, +3)
                unsigned int w0 = pack2bf(accOT[db][4*c]   * inv, accOT[db][4*c+1] * inv);
                unsigned int w1 = pack2bf(accOT[db][4*c+2] * inv, accOT[db][4*c+3] * inv);
                const int off = db * 32 + 8 * c + 4 * h32;
                *(unsigned int*)(Ot + row * 68 + off)     = w0;
                *(unsigned int*)(Ot + row * 68 + off + 2) = w1;
            }
    }
    __syncthreads();
    {
        const int row = t >> 1, col = (t & 1) * 32;
        uint4 o0 = *(const uint4*)(Ot + row * 68 + col);
        uint4 o1 = *(const uint4*)(Ot + row * 68 + col + 8);
        uint4 o2 = *(const uint4*)(Ot + row * 68 + col + 16);
        uint4 o3 = *(const uint4*)(Ot + row * 68 + col + 24);
        unsigned short* dst = Om + (size_t)(b * SEQ + q0 + row) * D_MODEL + h * DKH + col;
        *(uint4*)(dst)      = o0;
        *(uint4*)(dst + 8)  = o1;
        *(uint4*)(dst + 16) = o2;
        *(uint4*)(dst + 24) = o3;
    }
}

extern "C" void kernel_launch(void* const* d_in, const int* in_sizes, int n_in,
                              void* d_out, int out_size, void* d_ws, size_t ws_size,
                              hipStream_t stream) {
    const float* x   = (const float*)d_in[0];
    const float* w_q = (const float*)d_in[1];
    const float* w_k = (const float*)d_in[2];
    const float* w_v = (const float*)d_in[3];
    const float* w_o = (const float*)d_in[4];
    float* out = (float*)d_out;

    // ws (48 MB): xb 8 | weights 4x2 | Qb 8 | Kb 8 | VtG 8 | Ab 8
    unsigned short* xb  = (unsigned short*)d_ws;
    unsigned short* wqb = xb  + (size_t)MTOT * D_MODEL;
    unsigned short* wkb = wqb + (size_t)D_MODEL * D_MODEL;
    unsigned short* wvb = wkb + (size_t)D_MODEL * D_MODEL;
    unsigned short* wob = wvb + (size_t)D_MODEL * D_MODEL;
    unsigned short* Qb  = wob + (size_t)D_MODEL * D_MODEL;
    unsigned short* Kb  = Qb  + (size_t)MTOT * D_MODEL;
    unsigned short* VtG = Kb  + (size_t)MTOT * D_MODEL;   // V^T [1024][4096]
    unsigned short* Ab  = VtG + (size_t)MTOT * D_MODEL;

    dim3 blk(256);
    cvt_all<<<dim3(2048 + 4 * 512), blk, 0, stream>>>(
        x, w_q, w_k, w_v, w_o, xb, wqb, wkb, wvb, wob);
    // fused QKV projection; z==2 emits V^T = Wv @ x^T directly (VSWAP).
    // Q scale = (1/8) * log2(e) so attention can use exp2.
    gemm_bt<false, true><<<dim3(MTOT / 128, D_MODEL / 128, 3), blk, 0, stream>>>(
        xb, wqb, wkb, wvb, Qb, Kb, VtG, MTOT, D_MODEL, D_MODEL, 0.125f * 1.44269504f);
    // balanced causal flash attention (128-q blocks, full-key waves)
    attn_kernel<<<dim3(BATCH * NHEADS, 16), blk, 0, stream>>>(Qb, Kb, VtG, Ab);
    // output projection -> fp32
    gemm_bt<true, false><<<dim3(MTOT / 128, D_MODEL / 128, 1), blk, 0, stream>>>(
        Ab, wob, wob, wob, out, out, out, MTOT, D_MODEL, D_MODEL, 1.0f);
}

// Round 2
// 179.837 us; speedup vs baseline: 1.0605x; 1.0605x over previous
//
#include <hip/hip_runtime.h>
#include <hip/hip_bf16.h>
#include <stdint.h>

#define D_MODEL 1024
#define NHEADS  16
#define DKH     64
#define BATCH   2
#define SEQ     2048
#define MTOT    (BATCH*SEQ)   // 4096

typedef __attribute__((ext_vector_type(8)))  short bf16x8;   // 8 bf16 = 4 VGPRs
typedef __attribute__((ext_vector_type(4)))  float f32x4;
typedef __attribute__((ext_vector_type(16))) float f32x16;
typedef __attribute__((ext_vector_type(4)))  unsigned int u32x4;

__device__ inline unsigned short f2bf(float f) {
    __hip_bfloat16 h = __float2bfloat16(f);
    return *reinterpret_cast<unsigned short*>(&h);
}
__device__ inline unsigned int pack2bf(float a, float b) {   // low=a, high=b (RNE)
    __hip_bfloat162 h = __float22bfloat162_rn(float2{a, b});
    return *reinterpret_cast<unsigned int*>(&h);
}

// async global->LDS, 16B per lane; LDS dest = wave-uniform base + lane*16 (m97/m104)
__device__ inline void gl2lds16(const unsigned short* g, unsigned short* l) {
    __builtin_amdgcn_global_load_lds(
        (const __attribute__((address_space(1))) void*)g,
        (__attribute__((address_space(3))) void*)l,
        16, 0, 0);
}

// One-shot fp32 -> bf16 conversion of x and the 4 weight matrices.
__global__ __launch_bounds__(256) void cvt_all(
    const float* __restrict__ x,  const float* __restrict__ wq,
    const float* __restrict__ wk, const float* __restrict__ wv,
    const float* __restrict__ wo,
    unsigned short* __restrict__ xb,  unsigned short* __restrict__ wqb,
    unsigned short* __restrict__ wkb, unsigned short* __restrict__ wvb,
    unsigned short* __restrict__ wob)
{
    int bid = blockIdx.x;
    const float* s; unsigned short* d; size_t base;
    if (bid < 2048) { s = x; d = xb; base = (size_t)bid * 2048; }
    else {
        int w  = (bid - 2048) >> 9;
        int wb = (bid - 2048) & 511;
        s = (w == 0) ? wq : (w == 1) ? wk : (w == 2) ? wv : wo;
        d = (w == 0) ? wqb : (w == 1) ? wkb : (w == 2) ? wvb : wob;
        base = (size_t)wb * 2048;
    }
    size_t i = base + (size_t)threadIdx.x * 8;
    float4 a = *(const float4*)(s + i);
    float4 b = *(const float4*)(s + i + 4);
    unsigned short t8[8] = {f2bf(a.x), f2bf(a.y), f2bf(a.z), f2bf(a.w),
                            f2bf(b.x), f2bf(b.y), f2bf(b.z), f2bf(b.w)};
    *(uint4*)(d + i) = *(uint4*)t8;
}

// C[M,N] = scale * A[M,K] @ W[N,K]^T ; bf16 in, fp32 accum, C bf16 or fp32.
// BK=64 as two m97-style BK=32 sub-tiles (unpadded 128x32, global_load_lds w=16).
// VSWAP: blockIdx.z==2 computes C = W2 @ A^T (emits V^T directly).
template<bool CF32, bool VSWAP>
__global__ __launch_bounds__(256) void gemm_bt(
    const unsigned short* __restrict__ A,
    const unsigned short* __restrict__ W0,
    const unsigned short* __restrict__ W1,
    const unsigned short* __restrict__ W2,
    void* __restrict__ C0, void* __restrict__ C1, void* __restrict__ C2,
    int M, int N, int K, float scale0)
{
    const bool sw = VSWAP && (blockIdx.z == 2);
    const unsigned short* Aeff = sw ? W2 : A;
    const unsigned short* Weff = (blockIdx.z == 0) ? W0 : (blockIdx.z == 1 ? W1 : (sw ? A : W2));
    void* C = (blockIdx.z == 0) ? C0 : (blockIdx.z == 1 ? C1 : C2);
    const int Neff = sw ? M : N;
    const float scl = (blockIdx.z == 0) ? scale0 : 1.0f;
    const int m0 = (sw ? blockIdx.y : blockIdx.x) * 128;
    const int n0 = (sw ? blockIdx.x : blockIdx.y) * 128;

    __shared__ __align__(16) unsigned short As[2][128 * 32];
    __shared__ __align__(16) unsigned short Bs[2][128 * 32];

    const int t    = threadIdx.x;
    const int wave = t >> 6, lane = t & 63;
    const int quad = lane >> 4, l16 = lane & 15;
    const int wm   = (wave >> 1) * 64, wn = (wave & 1) * 64;

    const int srow = lane >> 2;
    const int schk = (lane & 3) * 8;   // shorts
    const unsigned short* Ag = Aeff + (size_t)(m0 + wave * 32 + srow) * K + schk;
    const unsigned short* Wg = Weff + (size_t)(n0 + wave * 32 + srow) * K + schk;
    const size_t rstep = (size_t)16 * K;
    unsigned short* AsB0 = &As[0][0] + wave * 1024;
    unsigned short* BsB0 = &Bs[0][0] + wave * 1024;

    f32x4 acc[4][4] = {};

    for (int k0 = 0; k0 < K; k0 += 64) {
        __syncthreads();
        #pragma unroll
        for (int s = 0; s < 2; ++s) {
            gl2lds16(Ag + k0 + s * 32,         AsB0 + s * 4096);
            gl2lds16(Ag + k0 + s * 32 + rstep, AsB0 + s * 4096 + 512);
            gl2lds16(Wg + k0 + s * 32,         BsB0 + s * 4096);
            gl2lds16(Wg + k0 + s * 32 + rstep, BsB0 + s * 4096 + 512);
        }
        __syncthreads();

        #pragma unroll
        for (int s = 0; s < 2; ++s) {
            bf16x8 afr[4], bfr[4];
            #pragma unroll
            for (int i = 0; i < 4; ++i) {
                afr[i] = *(const bf16x8*)(&As[s][0] + (wm + i * 16 + l16) * 32 + quad * 8);
                bfr[i] = *(const bf16x8*)(&Bs[s][0] + (wn + i * 16 + l16) * 32 + quad * 8);
            }
            #pragma unroll
            for (int i = 0; i < 4; ++i)
                #pragma unroll
                for (int j = 0; j < 4; ++j)
                    acc[i][j] = __builtin_amdgcn_mfma_f32_16x16x32_bf16(afr[i], bfr[j], acc[i][j], 0, 0, 0);
        }
    }

    #pragma unroll
    for (int i = 0; i < 4; ++i)
        #pragma unroll
        for (int j = 0; j < 4; ++j)
            #pragma unroll
            for (int r = 0; r < 4; ++r) {
                int row = m0 + wm + i * 16 + quad * 4 + r;
                int col = n0 + wn + j * 16 + l16;
                float v = acc[i][j][r] * scl;
                if (CF32) ((float*)C)[(size_t)row * Neff + col] = v;
                else      ((unsigned short*)C)[(size_t)row * Neff + col] = f2bf(v);
            }
}

// Flash causal attention, fixed-m softmax, 32x32x16 MFMA, split-key waves,
// transposed inner products (S^T = K Q^T, O^T = V^T P^T). ROUND-0 geometry
// (64-q blocks, 1024 blocks = 4/CU, balanced qt map — round-1's 128-q variant
// collapsed occupancy to 12% and regressed) + two new things:
//   1. double-buffered K/V LDS tiles: ONE barrier per 64-key tile (was 2),
//      ds_write staging of tile k+1 overlaps compute of tile k, global loads
//      for tile k+2 issued at tile top (2 iterations of latency cover).
//   2. softmax row-sum in 4 parallel accumulators (dep chain 16 -> 4).
// grid (32=b*h, 32=y balanced), block 256.
__global__ __launch_bounds__(256, 4) void attn_kernel(
    const unsigned short* __restrict__ Qm,
    const unsigned short* __restrict__ Km,
    const unsigned short* __restrict__ VtG,
    unsigned short* __restrict__ Om)
{
    const int bh = blockIdx.x;
    const int y  = blockIdx.y, g = y & 7, sl = y >> 3;
    const int qt = (sl == 0) ? 31 - g : (sl == 1) ? 16 + g : (sl == 2) ? 15 - g : g;
    const int h  = bh & 15;
    const int b  = bh >> 4;
    const int t     = threadIdx.x;
    const int wave  = t >> 6, lane = t & 63;
    const int qhalf = wave >> 1, khalf = wave & 1;
    const int l31   = lane & 31, h32 = lane >> 5;

    // [buf][0]=K tile [key][dk], [buf][1]=V^T tile [dk][key]; row stride 72
    __shared__ __align__(16) unsigned short S[2][2][64 * 72];   // 36864 B

    const size_t base = (size_t)b * SEQ * D_MODEL + (size_t)h * DKH;
    const unsigned short* Qh = Qm + base;
    const unsigned short* Kh = Km + base;
    const unsigned short* Vh = VtG + (size_t)h * DKH * MTOT + (size_t)b * SEQ;  // [dk][m]

    // Q B-frags (Q pre-scaled by log2e/8): B[n=q=l31][k=h32*8+j], 4 k-steps = dk 64
    const int qrow = qt * 64 + qhalf * 32 + l31;
    bf16x8 qf[4];
    #pragma unroll
    for (int ks = 0; ks < 4; ++ks)
        qf[ks] = *(const bf16x8*)(Qh + (size_t)qrow * D_MODEL + ks * 16 + h32 * 8);

    f32x16 accOT[2] = {};   // O^T partial: col=l31=q, row=(reg&3)+8*(reg>>2)+4*h32=dk (+32*db)
    float  la[4] = {0.f, 0.f, 0.f, 0.f};   // 4-way split row-sum partials

    const int srow = t >> 2, scol = (t & 3) * 16;
    const int kbase = khalf * 32;
    const int ntiles = qt + 1;

    // tile j lives in reg-set (j&1) then LDS buf (j&1)
    uint4 kA0, kA1, vA0, vA1, kB0, kB1, vB0, vB1;

    // prologue: tile0 -> set A -> S[0]; issue tile1 -> set B
    {
        const unsigned short* ksrc = Kh + (size_t)srow * D_MODEL + scol;
        kA0 = *(const uint4*)ksrc; kA1 = *(const uint4*)(ksrc + 8);
        const unsigned short* vsrc = Vh + (size_t)srow * MTOT + scol;
        vA0 = *(const uint4*)vsrc; vA1 = *(const uint4*)(vsrc + 8);
        *(uint4*)(&S[0][0][0] + srow * 72 + scol)     = kA0;
        *(uint4*)(&S[0][0][0] + srow * 72 + scol + 8) = kA1;
        *(uint4*)(&S[0][1][0] + srow * 72 + scol)     = vA0;
        *(uint4*)(&S[0][1][0] + srow * 72 + scol + 8) = vA1;
        if (ntiles > 1) {
            const unsigned short* k1 = Kh + (size_t)(64 + srow) * D_MODEL + scol;
            kB0 = *(const uint4*)k1; kB1 = *(const uint4*)(k1 + 8);
            const unsigned short* v1 = Vh + (size_t)srow * MTOT + 64 + scol;
            vB0 = *(const uint4*)v1; vB1 = *(const uint4*)(v1 + 8);
        }
    }
    __syncthreads();

    // One tile: issue loads (kt+2)->cur regs; compute cur buf; stage (kt+1)
    // from other regs into other buf; single barrier.
#define TILE_BODY(KT, CK0, CK1, CV0, CV1, NK0, NK1, NV0, NV1, KS, VT, KSN, VTN) \
    do {                                                                        \
        const int kt_ = (KT);                                                   \
        if (kt_ + 2 < ntiles) {                                                 \
            const unsigned short* ksrc = Kh + (size_t)((kt_ + 2) * 64 + srow) * D_MODEL + scol; \
            CK0 = *(const uint4*)ksrc; CK1 = *(const uint4*)(ksrc + 8);         \
            const unsigned short* vsrc = Vh + (size_t)srow * MTOT + (kt_ + 2) * 64 + scol;      \
            CV0 = *(const uint4*)vsrc; CV1 = *(const uint4*)(vsrc + 8);         \
        }                                                                       \
        const bool diag = (kt_ == qt);                                          \
        if (!(diag && khalf > qhalf)) {                                         \
            f32x16 sT = {};                                                     \
            _Pragma("unroll")                                                   \
            for (int ks = 0; ks < 4; ++ks) {                                    \
                bf16x8 kf = *(const bf16x8*)((KS) + (kbase + l31) * 72 + ks * 16 + h32 * 8);    \
                sT = __builtin_amdgcn_mfma_f32_32x32x16_bf16(kf, qf[ks], sT, 0, 0, 0);          \
            }                                                                   \
            const bool maskq = diag && (khalf == qhalf);                        \
            float pvv[16];                                                      \
            _Pragma("unroll")                                                   \
            for (int reg = 0; reg < 16; ++reg) {                                \
                const int rloc = (reg & 3) + 8 * (reg >> 2) + 4 * h32;          \
                float v = sT[reg];                                              \
                if (maskq) v = (rloc <= l31) ? v : -1e30f;                      \
                float p = exp2f(v);                                             \
                la[reg & 3] += p;                                               \
                pvv[reg] = p;                                                   \
            }                                                                   \
            unsigned int pk[8], pr[8];                                          \
            _Pragma("unroll")                                                   \
            for (int i = 0; i < 8; ++i) pk[i] = pack2bf(pvv[2 * i], pvv[2 * i + 1]);            \
            _Pragma("unroll")                                                   \
            for (int i = 0; i < 8; ++i) pr[i] = __shfl_xor(pk[i], 32, 64);      \
            _Pragma("unroll")                                                   \
            for (int ks2 = 0; ks2 < 2; ++ks2) {                                 \
                union { u32x4 u; bf16x8 b; } pf;                                \
                pf.u[0] = h32 ? pr[4 * ks2 + 2] : pk[4 * ks2 + 0];              \
                pf.u[1] = h32 ? pr[4 * ks2 + 3] : pk[4 * ks2 + 1];              \
                pf.u[2] = h32 ? pk[4 * ks2 + 2] : pr[4 * ks2 + 0];              \
                pf.u[3] = h32 ? pk[4 * ks2 + 3] : pr[4 * ks2 + 1];              \
                _Pragma("unroll")                                               \
                for (int db = 0; db < 2; ++db) {                                \
                    bf16x8 vf = *(const bf16x8*)((VT) + (db * 32 + l31) * 72 + kbase + ks2 * 16 + h32 * 8); \
                    accOT[db] = __builtin_amdgcn_mfma_f32_32x32x16_bf16(vf, pf.b, accOT[db], 0, 0, 0);      \
                }                                                               \
            }                                                                   \
        }                                                                       \
        if (kt_ + 1 < ntiles) {                                                 \
            *(uint4*)((KSN) + srow * 72 + scol)     = NK0;                      \
            *(uint4*)((KSN) + srow * 72 + scol + 8) = NK1;                      \
            *(uint4*)((VTN) + srow * 72 + scol)     = NV0;                      \
            *(uint4*)((VTN) + srow * 72 + scol + 8) = NV1;                      \
        }                                                                       \
        __syncthreads();                                                        \
    } while (0)

    for (int kt = 0; kt < ntiles; kt += 2) {
        TILE_BODY(kt, kA0, kA1, vA0, vA1, kB0, kB1, vB0, vB1,
                  &S[0][0][0], &S[0][1][0], &S[1][0][0], &S[1][1][0]);
        if (kt + 1 < ntiles)
            TILE_BODY(kt + 1, kB0, kB1, vB0, vB1, kA0, kA1, vA0, vA1,
                      &S[1][0][0], &S[1][1][0], &S[0][0][0], &S[0][1][0]);
    }
#undef TILE_BODY

    float l_s = (la[0] + la[1]) + (la[2] + la[3]);

    // ---- merge key halves (khalf 1 -> 0) through dead S[0] ----
    float* exO = (qhalf == 0) ? (float*)&S[0][0][0] : (float*)&S[0][1][0];
    if (khalf == 1) {
        #pragma unroll
        for (int db = 0; db < 2; ++db)
            #pragma unroll
            for (int c = 0; c < 4; ++c) {
                float4 v = { accOT[db][c*4], accOT[db][c*4+1], accOT[db][c*4+2], accOT[db][c*4+3] };
                *(float4*)(exO + lane * 36 + db * 16 + c * 4) = v;
            }
        exO[lane * 36 + 32] = l_s;
    }
    __syncthreads();
    float inv = 0.f;
    if (khalf == 0) {
        #pragma unroll
        for (int db = 0; db < 2; ++db)
            #pragma unroll
            for (int c = 0; c < 4; ++c) {
                float4 v = *(const float4*)(exO + lane * 36 + db * 16 + c * 4);
                accOT[db][c*4]   += v.x; accOT[db][c*4+1] += v.y;
                accOT[db][c*4+2] += v.z; accOT[db][c*4+3] += v.w;
            }
        l_s += exO[lane * 36 + 32];
        l_s += __shfl_xor(l_s, 32, 64);   // other h32 half of the same q
        inv = 1.f / l_s;
    }
    __syncthreads();   // merge reads done; S[0] free for the transpose tile

    // ---- transpose O^T -> [q][dk] bf16 tile in S[0], then coalesced store ----
    unsigned short* Ot = &S[0][0][0];   // [64][68] u16
    if (khalf == 0) {
        const int row = qhalf * 32 + l31;
        #pragma unroll
        for (int db = 0; db < 2; ++db)
            #pragma unroll
            for (int c = 0; c < 4; ++c) {
                // dk pairs: (8c+4*h32, +1) and (+2, +3)
                unsigned int w0 = pack2bf(accOT[db][4*c]   * inv, accOT[db][4*c+1] * inv);
                unsigned int w1 = pack2bf(accOT[db][4*c+2] * inv, accOT[db][4*c+3] * inv);
                const int off = db * 32 + 8 * c + 4 * h32;
                *(unsigned int*)(Ot + row * 68 + off)     = w0;
                *(unsigned int*)(Ot + row * 68 + off + 2) = w1;
            }
    }
    __syncthreads();
    {
        const int row = t >> 2, col = (t & 3) * 16;
        uint4 o0 = *(const uint4*)(Ot + row * 68 + col);
        uint4 o1 = *(const uint4*)(Ot + row * 68 + col + 8);
        unsigned short* dst = Om + (size_t)(b * SEQ + qt * 64 + row) * D_MODEL + h * DKH + col;
        *(uint4*)(dst)     = o0;
        *(uint4*)(dst + 8) = o1;
    }
}

extern "C" void kernel_launch(void* const* d_in, const int* in_sizes, int n_in,
                              void* d_out, int out_size, void* d_ws, size_t ws_size,
                              hipStream_t stream) {
    const float* x   = (const float*)d_in[0];
    const float* w_q = (const float*)d_in[1];
    const float* w_k = (const float*)d_in[2];
    const float* w_v = (const float*)d_in[3];
    const float* w_o = (const float*)d_in[4];
    float* out = (float*)d_out;

    // ws (48 MB): xb 8 | weights 4x2 | Qb 8 | Kb 8 | VtG 8 | Ab 8
    unsigned short* xb  = (unsigned short*)d_ws;
    unsigned short* wqb = xb  + (size_t)MTOT * D_MODEL;
    unsigned short* wkb = wqb + (size_t)D_MODEL * D_MODEL;
    unsigned short* wvb = wkb + (size_t)D_MODEL * D_MODEL;
    unsigned short* wob = wvb + (size_t)D_MODEL * D_MODEL;
    unsigned short* Qb  = wob + (size_t)D_MODEL * D_MODEL;
    unsigned short* Kb  = Qb  + (size_t)MTOT * D_MODEL;
    unsigned short* VtG = Kb  + (size_t)MTOT * D_MODEL;   // V^T [1024][4096]
    unsigned short* Ab  = VtG + (size_t)MTOT * D_MODEL;

    dim3 blk(256);
    cvt_all<<<dim3(2048 + 4 * 512), blk, 0, stream>>>(
        x, w_q, w_k, w_v, w_o, xb, wqb, wkb, wvb, wob);
    // fused QKV projection; z==2 emits V^T = Wv @ x^T directly (VSWAP).
    // Q scale = (1/8) * log2(e) so attention can use exp2.
    gemm_bt<false, true><<<dim3(MTOT / 128, D_MODEL / 128, 3), blk, 0, stream>>>(
        xb, wqb, wkb, wvb, Qb, Kb, VtG, MTOT, D_MODEL, D_MODEL, 0.125f * 1.44269504f);
    // balanced causal flash attention (dbuf K/V, 1 barrier/tile, split-key waves)
    attn_kernel<<<dim3(BATCH * NHEADS, 32), blk, 0, stream>>>(Qb, Kb, VtG, Ab);
    // output projection -> fp32
    gemm_bt<true, false><<<dim3(MTOT / 128, D_MODEL / 128, 1), blk, 0, stream>>>(
        Ab, wob, wob, wob, out, out, out, MTOT, D_MODEL, D_MODEL, 1.0f);
}

// Round 3
// 179.025 us; speedup vs baseline: 1.0653x; 1.0045x over previous
//
#include <hip/hip_runtime.h>
#include <hip/hip_bf16.h>
#include <stdint.h>

#define D_MODEL 1024
#define NHEADS  16
#define DKH     64
#define BATCH   2
#define SEQ     2048
#define MTOT    (BATCH*SEQ)   // 4096

typedef __attribute__((ext_vector_type(8)))  short bf16x8;   // 8 bf16 = 4 VGPRs
typedef __attribute__((ext_vector_type(4)))  float f32x4;
typedef __attribute__((ext_vector_type(16))) float f32x16;
typedef __attribute__((ext_vector_type(4)))  unsigned int u32x4;

__device__ inline unsigned short f2bf(float f) {
    __hip_bfloat16 h = __float2bfloat16(f);
    return *reinterpret_cast<unsigned short*>(&h);
}
__device__ inline unsigned int pack2bf(float a, float b) {   // low=a, high=b (RNE)
    __hip_bfloat162 h = __float22bfloat162_rn(float2{a, b});
    return *reinterpret_cast<unsigned int*>(&h);
}

// async global->LDS, 16B per lane; LDS dest = wave-uniform base + lane*16 (m97/m104)
__device__ inline void gl2lds16(const unsigned short* g, unsigned short* l) {
    __builtin_amdgcn_global_load_lds(
        (const __attribute__((address_space(1))) void*)g,
        (__attribute__((address_space(3))) void*)l,
        16, 0, 0);
}

// One-shot fp32 -> bf16 conversion of x and the 4 weight matrices.
__global__ __launch_bounds__(256) void cvt_all(
    const float* __restrict__ x,  const float* __restrict__ wq,
    const float* __restrict__ wk, const float* __restrict__ wv,
    const float* __restrict__ wo,
    unsigned short* __restrict__ xb,  unsigned short* __restrict__ wqb,
    unsigned short* __restrict__ wkb, unsigned short* __restrict__ wvb,
    unsigned short* __restrict__ wob)
{
    int bid = blockIdx.x;
    const float* s; unsigned short* d; size_t base;
    if (bid < 2048) { s = x; d = xb; base = (size_t)bid * 2048; }
    else {
        int w  = (bid - 2048) >> 9;
        int wb = (bid - 2048) & 511;
        s = (w == 0) ? wq : (w == 1) ? wk : (w == 2) ? wv : wo;
        d = (w == 0) ? wqb : (w == 1) ? wkb : (w == 2) ? wvb : wob;
        base = (size_t)wb * 2048;
    }
    size_t i = base + (size_t)threadIdx.x * 8;
    float4 a = *(const float4*)(s + i);
    float4 b = *(const float4*)(s + i + 4);
    unsigned short t8[8] = {f2bf(a.x), f2bf(a.y), f2bf(a.z), f2bf(a.w),
                            f2bf(b.x), f2bf(b.y), f2bf(b.z), f2bf(b.w)};
    *(uint4*)(d + i) = *(uint4*)t8;
}

// Fused QKV projection. Block (i,j): stage x-tile[i] ONCE + wq/wk/wv tiles[j],
// compute Q[i,j], K[i,j] = x@W^T and V^T[j,i] via operand-swapped MFMA
// (A=wv-frag, B=x-frag -> C[wv-row][x-row], the verified VSWAP trick in-block).
// 3x MFMA per staged byte vs the separate-z version. 8 waves (512 thr),
// wave quadrant: wm=(w>>2)*64 x-rows, wn=(w&3)*32 weight-rows.
// grid (32, 8) = 256 blocks = 1/CU, 8 waves/CU = 2/SIMD.
__global__ __launch_bounds__(512, 2) void qkv_fused(
    const unsigned short* __restrict__ X,
    const unsigned short* __restrict__ Wq,
    const unsigned short* __restrict__ Wk,
    const unsigned short* __restrict__ Wv,
    unsigned short* __restrict__ Qo,
    unsigned short* __restrict__ Ko,
    unsigned short* __restrict__ Vto,
    float qscale)
{
    const int m0 = blockIdx.x * 128;   // x-row tile
    const int n0 = blockIdx.y * 128;   // weight-row tile

    __shared__ __align__(16) unsigned short Xs[2][128 * 32];   // [ksub][row][32]
    __shared__ __align__(16) unsigned short Bq[2][128 * 32];
    __shared__ __align__(16) unsigned short Bk[2][128 * 32];
    __shared__ __align__(16) unsigned short Bv[2][128 * 32];   // 64 KiB total

    const int t = threadIdx.x;
    const int wave = t >> 6, lane = t & 63;
    const int quad = lane >> 4, l16 = lane & 15;
    const int wm = (wave >> 2) * 64;
    const int wn = (wave & 3) * 32;

    // staging: wave w covers tile (w>>1), rows [(w&1)*64, +64) in 4 groups of 16
    const int stile = wave >> 1;
    const int srow  = (wave & 1) * 64 + (lane >> 2);
    const int schk  = (lane & 3) * 8;
    const unsigned short* gsrc = (stile == 0) ? X : (stile == 1) ? Wq :
                                 (stile == 2) ? Wk : Wv;
    const int grow0 = (stile == 0) ? m0 : n0;
    const unsigned short* Sg = gsrc + (size_t)(grow0 + srow) * D_MODEL + schk;
    unsigned short* Ld = ((stile == 0) ? &Xs[0][0] : (stile == 1) ? &Bq[0][0] :
                          (stile == 2) ? &Bk[0][0] : &Bv[0][0])
                         + (wave & 1) * 64 * 32;   // wave-uniform base

    f32x4 aQ[4][2] = {}, aK[4][2] = {}, aV[2][4] = {};

    for (int k0 = 0; k0 < D_MODEL; k0 += 64) {
        __syncthreads();
        #pragma unroll
        for (int s = 0; s < 2; ++s)
            #pragma unroll
            for (int g = 0; g < 4; ++g)
                gl2lds16(Sg + k0 + s * 32 + (size_t)g * 16 * D_MODEL,
                         Ld + s * 4096 + g * 512);
        __syncthreads();

        #pragma unroll
        for (int s = 0; s < 2; ++s) {
            bf16x8 xa[4], fq[2], fk[2], fv[2];
            #pragma unroll
            for (int i = 0; i < 4; ++i)
                xa[i] = *(const bf16x8*)(&Xs[s][0] + (wm + i * 16 + l16) * 32 + quad * 8);
            #pragma unroll
            for (int j = 0; j < 2; ++j) {
                fq[j] = *(const bf16x8*)(&Bq[s][0] + (wn + j * 16 + l16) * 32 + quad * 8);
                fk[j] = *(const bf16x8*)(&Bk[s][0] + (wn + j * 16 + l16) * 32 + quad * 8);
                fv[j] = *(const bf16x8*)(&Bv[s][0] + (wn + j * 16 + l16) * 32 + quad * 8);
            }
            #pragma unroll
            for (int i = 0; i < 4; ++i)
                #pragma unroll
                for (int j = 0; j < 2; ++j) {
                    aQ[i][j] = __builtin_amdgcn_mfma_f32_16x16x32_bf16(xa[i], fq[j], aQ[i][j], 0, 0, 0);
                    aK[i][j] = __builtin_amdgcn_mfma_f32_16x16x32_bf16(xa[i], fk[j], aK[i][j], 0, 0, 0);
                    aV[j][i] = __builtin_amdgcn_mfma_f32_16x16x32_bf16(fv[j], xa[i], aV[j][i], 0, 0, 0);
                }
        }
    }

    #pragma unroll
    for (int i = 0; i < 4; ++i)
        #pragma unroll
        for (int j = 0; j < 2; ++j)
            #pragma unroll
            for (int r = 0; r < 4; ++r) {
                const int mr = m0 + wm + i * 16 + quad * 4 + r;
                const int nc = n0 + wn + j * 16 + l16;
                Qo[(size_t)mr * D_MODEL + nc] = f2bf(aQ[i][j][r] * qscale);
                Ko[(size_t)mr * D_MODEL + nc] = f2bf(aK[i][j][r]);
                // V^T: row = weight-side of aV, col = x-side
                Vto[(size_t)(n0 + wn + j * 16 + quad * 4 + r) * MTOT
                    + (m0 + wm + i * 16 + l16)] = f2bf(aV[j][i][r]);
            }
}

// Output projection C_fp32[M,N] = A[M,K] @ W[N,K]^T, 128^2 tile, 8 waves
// (512 thr) so the fixed 256-block grid still yields 2 waves/SIMD (the old
// 256-thread version ran at 1 wave/SIMD -> latency-exposed).
__global__ __launch_bounds__(512, 2) void gemm_o(
    const unsigned short* __restrict__ A,
    const unsigned short* __restrict__ W,
    float* __restrict__ C)
{
    const int m0 = blockIdx.x * 128, n0 = blockIdx.y * 128;
    __shared__ __align__(16) unsigned short As[2][128 * 32];
    __shared__ __align__(16) unsigned short Bs[2][128 * 32];

    const int t = threadIdx.x, wave = t >> 6, lane = t & 63;
    const int quad = lane >> 4, l16 = lane & 15;
    const int wm = (wave >> 2) * 64, wn = (wave & 3) * 32;

    // staging: wave w covers tile (w>>2), rows [(w&3)*32, +32) in 2 groups of 16
    const int stile = wave >> 2;
    const int srow  = (wave & 3) * 32 + (lane >> 2);
    const int schk  = (lane & 3) * 8;
    const unsigned short* gsrc = stile ? W : A;
    const int grow0 = stile ? n0 : m0;
    const unsigned short* Sg = gsrc + (size_t)(grow0 + srow) * D_MODEL + schk;
    unsigned short* Ld = (stile ? &Bs[0][0] : &As[0][0]) + (wave & 3) * 32 * 32;

    f32x4 acc[4][2] = {};

    for (int k0 = 0; k0 < D_MODEL; k0 += 64) {
        __syncthreads();
        #pragma unroll
        for (int s = 0; s < 2; ++s)
            #pragma unroll
            for (int g = 0; g < 2; ++g)
                gl2lds16(Sg + k0 + s * 32 + (size_t)g * 16 * D_MODEL,
                         Ld + s * 4096 + g * 512);
        __syncthreads();

        #pragma unroll
        for (int s = 0; s < 2; ++s) {
            bf16x8 af[4], bfr[2];
            #pragma unroll
            for (int i = 0; i < 4; ++i)
                af[i] = *(const bf16x8*)(&As[s][0] + (wm + i * 16 + l16) * 32 + quad * 8);
            #pragma unroll
            for (int j = 0; j < 2; ++j)
                bfr[j] = *(const bf16x8*)(&Bs[s][0] + (wn + j * 16 + l16) * 32 + quad * 8);
            #pragma unroll
            for (int i = 0; i < 4; ++i)
                #pragma unroll
                for (int j = 0; j < 2; ++j)
                    acc[i][j] = __builtin_amdgcn_mfma_f32_16x16x32_bf16(af[i], bfr[j], acc[i][j], 0, 0, 0);
        }
    }

    #pragma unroll
    for (int i = 0; i < 4; ++i)
        #pragma unroll
        for (int j = 0; j < 2; ++j)
            #pragma unroll
            for (int r = 0; r < 4; ++r)
                C[(size_t)(m0 + wm + i * 16 + quad * 4 + r) * D_MODEL
                  + n0 + wn + j * 16 + l16] = acc[i][j][r];
}

// Flash causal attention — EXACT round-0 verified kernel (64-q blocks,
// split-key waves, 2-barrier tile loop, 18 KiB LDS = 8-block/CU capacity for
// tail absorption), plus one safe tweak: 4-way split row-sum accumulators
// (f32 add dep chain 16 -> 4). grid (32=b*h, 32=y balanced), block 256.
__global__ __launch_bounds__(256, 4) void attn_kernel(
    const unsigned short* __restrict__ Qm,
    const unsigned short* __restrict__ Km,
    const unsigned short* __restrict__ VtG,
    unsigned short* __restrict__ Om)
{
    const int bh = blockIdx.x;
    const int y  = blockIdx.y, g = y & 7, sl = y >> 3;
    const int qt = (sl == 0) ? 31 - g : (sl == 1) ? 16 + g : (sl == 2) ? 15 - g : g;
    const int h  = bh & 15;
    const int b  = bh >> 4;
    const int t     = threadIdx.x;
    const int wave  = t >> 6, lane = t & 63;
    const int qhalf = wave >> 1, khalf = wave & 1;
    const int l31   = lane & 31, h32 = lane >> 5;

    __shared__ __align__(16) unsigned short Ks[64 * 72];      // K tile [key][dk]
    __shared__ __align__(16) unsigned short Vt[64 * 72];      // V^T tile [dk][key]

    const size_t base = (size_t)b * SEQ * D_MODEL + (size_t)h * DKH;
    const unsigned short* Qh = Qm + base;
    const unsigned short* Kh = Km + base;
    const unsigned short* Vh = VtG + (size_t)h * DKH * MTOT + (size_t)b * SEQ;  // [dk][m]

    // Q B-frags (Q pre-scaled by log2e/8): B[n=q=l31][k=h32*8+j], 4 k-steps = dk 64
    const int qrow = qt * 64 + qhalf * 32 + l31;
    bf16x8 qf[4];
    #pragma unroll
    for (int ks = 0; ks < 4; ++ks)
        qf[ks] = *(const bf16x8*)(Qh + (size_t)qrow * D_MODEL + ks * 16 + h32 * 8);

    f32x16 accOT[2] = {};   // O^T partial: col=l31=q, row=(reg&3)+8*(reg>>2)+4*h32=dk (+32*db)
    float  la[4] = {0.f, 0.f, 0.f, 0.f};   // 4-way split row-sum partials

    const int srow = t >> 2, scol = (t & 3) * 16;
    const int kbase = khalf * 32;

    // prefetch K/V tile 0 into regs
    uint4 kr0, kr1, vr0, vr1;
    {
        const unsigned short* ks = Kh + (size_t)srow * D_MODEL + scol;
        kr0 = *(const uint4*)ks; kr1 = *(const uint4*)(ks + 8);
        const unsigned short* vs = Vh + (size_t)srow * MTOT + scol;
        vr0 = *(const uint4*)vs; vr1 = *(const uint4*)(vs + 8);
    }

    for (int kt = 0; kt <= qt; ++kt) {
        __syncthreads();   // prior iter's frag reads done
        *(uint4*)(Ks + srow * 72 + scol)     = kr0;
        *(uint4*)(Ks + srow * 72 + scol + 8) = kr1;
        *(uint4*)(Vt + srow * 72 + scol)     = vr0;
        *(uint4*)(Vt + srow * 72 + scol + 8) = vr1;
        __syncthreads();

        if (kt < qt) {     // prefetch next tile; overlaps compute below
            const unsigned short* ks = Kh + (size_t)((kt + 1) * 64 + srow) * D_MODEL + scol;
            kr0 = *(const uint4*)ks; kr1 = *(const uint4*)(ks + 8);
            const unsigned short* vs = Vh + (size_t)srow * MTOT + (kt + 1) * 64 + scol;
            vr0 = *(const uint4*)vs; vr1 = *(const uint4*)(vs + 8);
        }

        const bool diag = (kt == qt);
        if (diag && khalf > qhalf) continue;   // fully-masked quarter: skip

        // S^T = K Q^T : A=K rows (same LDS bytes as before, roles swapped)
        f32x16 sT = {};
        #pragma unroll
        for (int ks = 0; ks < 4; ++ks) {
            bf16x8 kf = *(const bf16x8*)(Ks + (kbase + l31) * 72 + ks * 16 + h32 * 8);
            sT = __builtin_amdgcn_mfma_f32_32x32x16_bf16(kf, qf[ks], sT, 0, 0, 0);
        }

        // p = exp2(s); mask on equal-half diag quarter: keep key(rloc) <= q(l31)
        const bool maskq = diag && (khalf == qhalf);
        float pv[16];
        #pragma unroll
        for (int reg = 0; reg < 16; ++reg) {
            const int rloc = (reg & 3) + 8 * (reg >> 2) + 4 * h32;   // key_local
            float v = sT[reg];
            if (maskq) v = (rloc <= l31) ? v : -1e30f;
            float p = exp2f(v);
            la[reg & 3] += p;
            pv[reg] = p;
        }
        // pack pairs (consecutive regs = consecutive keys) and half-wave exchange
        unsigned int pk[8], pr[8];
        #pragma unroll
        for (int i = 0; i < 8; ++i) pk[i] = pack2bf(pv[2 * i], pv[2 * i + 1]);
        #pragma unroll
        for (int i = 0; i < 8; ++i) pr[i] = __shfl_xor(pk[i], 32, 64);

        // O^T += V^T P^T : A = V^T rows (same bytes as before), B = P^T in regs
        #pragma unroll
        for (int ks2 = 0; ks2 < 2; ++ks2) {
            union { u32x4 u; bf16x8 b; } pf;
            pf.u[0] = h32 ? pr[4 * ks2 + 2] : pk[4 * ks2 + 0];
            pf.u[1] = h32 ? pr[4 * ks2 + 3] : pk[4 * ks2 + 1];
            pf.u[2] = h32 ? pk[4 * ks2 + 2] : pr[4 * ks2 + 0];
            pf.u[3] = h32 ? pk[4 * ks2 + 3] : pr[4 * ks2 + 1];
            #pragma unroll
            for (int db = 0; db < 2; ++db) {
                bf16x8 vf = *(const bf16x8*)(Vt + (db * 32 + l31) * 72 + kbase + ks2 * 16 + h32 * 8);
                accOT[db] = __builtin_amdgcn_mfma_f32_32x32x16_bf16(vf, pf.b, accOT[db], 0, 0, 0);
            }
        }
    }

    float l_s = (la[0] + la[1]) + (la[2] + la[3]);

    // ---- merge key halves (khalf 1 -> 0) through dead Ks/Vt ----
    __syncthreads();
    float* exO = (qhalf == 0) ? (float*)Ks : (float*)Vt;   // 64 lanes x 36 floats (32 O + l + pad)
    if (khalf == 1) {
        #pragma unroll
        for (int db = 0; db < 2; ++db)
            #pragma unroll
            for (int c = 0; c < 4; ++c) {
                float4 v = { accOT[db][c*4], accOT[db][c*4+1], accOT[db][c*4+2], accOT[db][c*4+3] };
                *(float4*)(exO + lane * 36 + db * 16 + c * 4) = v;
            }
        exO[lane * 36 + 32] = l_s;
    }
    __syncthreads();
    float inv = 0.f;
    if (khalf == 0) {
        #pragma unroll
        for (int db = 0; db < 2; ++db)
            #pragma unroll
            for (int c = 0; c < 4; ++c) {
                float4 v = *(const float4*)(exO + lane * 36 + db * 16 + c * 4);
                accOT[db][c*4]   += v.x; accOT[db][c*4+1] += v.y;
                accOT[db][c*4+2] += v.z; accOT[db][c*4+3] += v.w;
            }
        l_s += exO[lane * 36 + 32];
        l_s += __shfl_xor(l_s, 32, 64);   // other h32 half of the same q
        inv = 1.f / l_s;
    }
    __syncthreads();   // merge reads done; Ks free for the transpose tile

    // ---- transpose O^T -> [q][dk] bf16 tile in Ks, then coalesced store ----
    unsigned short* Ot = Ks;   // [64][68] u16
    if (khalf == 0) {
        const int row = qhalf * 32 + l31;
        #pragma unroll
        for (int db = 0; db < 2; ++db)
            #pragma unroll
            for (int c = 0; c < 4; ++c) {
                // dk pairs: (8c+4*h32, +1) and (+2, +3)
                unsigned int w0 = pack2bf(accOT[db][4*c]   * inv, accOT[db][4*c+1] * inv);
                unsigned int w1 = pack2bf(accOT[db][4*c+2] * inv, accOT[db][4*c+3] * inv);
                const int off = db * 32 + 8 * c + 4 * h32;
                *(unsigned int*)(Ot + row * 68 + off)     = w0;
                *(unsigned int*)(Ot + row * 68 + off + 2) = w1;
            }
    }
    __syncthreads();
    {
        const int row = t >> 2, col = (t & 3) * 16;
        uint4 o0 = *(const uint4*)(Ot + row * 68 + col);
        uint4 o1 = *(const uint4*)(Ot + row * 68 + col + 8);
        unsigned short* dst = Om + (size_t)(b * SEQ + qt * 64 + row) * D_MODEL + h * DKH + col;
        *(uint4*)(dst)     = o0;
        *(uint4*)(dst + 8) = o1;
    }
}

extern "C" void kernel_launch(void* const* d_in, const int* in_sizes, int n_in,
                              void* d_out, int out_size, void* d_ws, size_t ws_size,
                              hipStream_t stream) {
    const float* x   = (const float*)d_in[0];
    const float* w_q = (const float*)d_in[1];
    const float* w_k = (const float*)d_in[2];
    const float* w_v = (const float*)d_in[3];
    const float* w_o = (const float*)d_in[4];
    float* out = (float*)d_out;

    // ws (48 MB): xb 8 | weights 4x2 | Qb 8 | Kb 8 | VtG 8 | Ab 8
    unsigned short* xb  = (unsigned short*)d_ws;
    unsigned short* wqb = xb  + (size_t)MTOT * D_MODEL;
    unsigned short* wkb = wqb + (size_t)D_MODEL * D_MODEL;
    unsigned short* wvb = wkb + (size_t)D_MODEL * D_MODEL;
    unsigned short* wob = wvb + (size_t)D_MODEL * D_MODEL;
    unsigned short* Qb  = wob + (size_t)D_MODEL * D_MODEL;
    unsigned short* Kb  = Qb  + (size_t)MTOT * D_MODEL;
    unsigned short* VtG = Kb  + (size_t)MTOT * D_MODEL;   // V^T [1024][4096]
    unsigned short* Ab  = VtG + (size_t)MTOT * D_MODEL;

    cvt_all<<<dim3(2048 + 4 * 512), dim3(256), 0, stream>>>(
        x, w_q, w_k, w_v, w_o, xb, wqb, wkb, wvb, wob);
    // fused QKV projection: x-tile staged once for Q, K, and V^T (in-block VSWAP).
    // Q scale = (1/8) * log2(e) so attention can use exp2.
    qkv_fused<<<dim3(MTOT / 128, D_MODEL / 128), dim3(512), 0, stream>>>(
        xb, wqb, wkb, wvb, Qb, Kb, VtG, 0.125f * 1.44269504f);
    // balanced causal flash attention (round-0 verified structure)
    attn_kernel<<<dim3(BATCH * NHEADS, 32), dim3(256), 0, stream>>>(Qb, Kb, VtG, Ab);
    // output projection -> fp32 (8-wave blocks: 2 waves/SIMD at 256 blocks)
    gemm_o<<<dim3(MTOT / 128, D_MODEL / 128), dim3(512), 0, stream>>>(Ab, wob, out);
}

// Round 4
// 168.708 us; speedup vs baseline: 1.1304x; 1.0612x over previous
//
#include <hip/hip_runtime.h>
#include <hip/hip_bf16.h>
#include <stdint.h>

#define D_MODEL 1024
#define NHEADS  16
#define DKH     64
#define BATCH   2
#define SEQ     2048
#define MTOT    (BATCH*SEQ)   // 4096

typedef __attribute__((ext_vector_type(8)))  short bf16x8;   // 8 bf16 = 4 VGPRs
typedef __attribute__((ext_vector_type(4)))  float f32x4;
typedef __attribute__((ext_vector_type(16))) float f32x16;
typedef __attribute__((ext_vector_type(4)))  unsigned int u32x4;

__device__ inline unsigned short f2bf(float f) {
    __hip_bfloat16 h = __float2bfloat16(f);
    return *reinterpret_cast<unsigned short*>(&h);
}
__device__ inline unsigned int pack2bf(float a, float b) {   // low=a, high=b (RNE)
    __hip_bfloat162 h = __float22bfloat162_rn(float2{a, b});
    return *reinterpret_cast<unsigned int*>(&h);
}

// async global->LDS, 16B per lane; LDS dest = wave-uniform base + lane*16 (m97/m104)
__device__ inline void gl2lds16(const unsigned short* g, unsigned short* l) {
    __builtin_amdgcn_global_load_lds(
        (const __attribute__((address_space(1))) void*)g,
        (__attribute__((address_space(3))) void*)l,
        16, 0, 0);
}

// One-shot fp32 -> bf16 conversion of x and the 4 weight matrices.
__global__ __launch_bounds__(256) void cvt_all(
    const float* __restrict__ x,  const float* __restrict__ wq,
    const float* __restrict__ wk, const float* __restrict__ wv,
    const float* __restrict__ wo,
    unsigned short* __restrict__ xb,  unsigned short* __restrict__ wqb,
    unsigned short* __restrict__ wkb, unsigned short* __restrict__ wvb,
    unsigned short* __restrict__ wob)
{
    int bid = blockIdx.x;
    const float* s; unsigned short* d; size_t base;
    if (bid < 2048) { s = x; d = xb; base = (size_t)bid * 2048; }
    else {
        int w  = (bid - 2048) >> 9;
        int wb = (bid - 2048) & 511;
        s = (w == 0) ? wq : (w == 1) ? wk : (w == 2) ? wv : wo;
        d = (w == 0) ? wqb : (w == 1) ? wkb : (w == 2) ? wvb : wob;
        base = (size_t)wb * 2048;
    }
    size_t i = base + (size_t)threadIdx.x * 8;
    float4 a = *(const float4*)(s + i);
    float4 b = *(const float4*)(s + i + 4);
    unsigned short t8[8] = {f2bf(a.x), f2bf(a.y), f2bf(a.z), f2bf(a.w),
                            f2bf(b.x), f2bf(b.y), f2bf(b.z), f2bf(b.w)};
    *(uint4*)(d + i) = *(uint4*)t8;
}

// Fused QKV projection, 2-PHASE pipelined (T3/T4 minimum recipe):
// K-step = 32, LDS double-buffered per tile; each step ISSUES next-step
// global_load_lds BEFORE the current step's ds_read+MFMA, one barrier/step.
// The implicit vmcnt(0) in __syncthreads lands after a full compute phase of
// latency cover (round-3's version drained immediately after issue -> 21%
// MfmaUtil at 1 block/CU). x-tile still staged once for Q, K, V^T (VSWAP).
// Bijective XCD swizzle: each XCD owns one weight-column j.
// grid (32, 8) = 256 blocks, 512 thr (8 waves: wm=(w>>2)*64, wn=(w&3)*32).
__global__ __launch_bounds__(512, 2) void qkv_fused(
    const unsigned short* __restrict__ X,
    const unsigned short* __restrict__ Wq,
    const unsigned short* __restrict__ Wk,
    const unsigned short* __restrict__ Wv,
    unsigned short* __restrict__ Qo,
    unsigned short* __restrict__ Ko,
    unsigned short* __restrict__ Vto,
    float qscale)
{
    const int id = blockIdx.x + 32 * blockIdx.y;   // 256 blocks, 256%8==0
    const int sw = (id & 7) * 32 + (id >> 3);      // XCD c -> contiguous chunk (bj=c)
    const int m0 = (sw & 31) * 128;                // x-row tile
    const int n0 = (sw >> 5) * 128;                // weight-row tile

    // [buf][128 x 32 shorts] per tile; 4 tiles x 2 buf = 64 KiB
    __shared__ __align__(16) unsigned short Xs[2][128 * 32];
    __shared__ __align__(16) unsigned short Bq[2][128 * 32];
    __shared__ __align__(16) unsigned short Bk[2][128 * 32];
    __shared__ __align__(16) unsigned short Bv[2][128 * 32];

    const int t = threadIdx.x;
    const int wave = t >> 6, lane = t & 63;
    const int quad = lane >> 4, l16 = lane & 15;
    const int wm = (wave >> 2) * 64;
    const int wn = (wave & 3) * 32;

    // staging: wave w covers tile (w>>1), rows [(w&1)*64, +64) in 4 groups of 16
    const int stile = wave >> 1;
    const int srow  = (wave & 1) * 64 + (lane >> 2);
    const int schk  = (lane & 3) * 8;
    const unsigned short* gsrc = (stile == 0) ? X : (stile == 1) ? Wq :
                                 (stile == 2) ? Wk : Wv;
    const int grow0 = (stile == 0) ? m0 : n0;
    const unsigned short* Sg = gsrc + (size_t)(grow0 + srow) * D_MODEL + schk;
    unsigned short* LdB = ((stile == 0) ? &Xs[0][0] : (stile == 1) ? &Bq[0][0] :
                           (stile == 2) ? &Bk[0][0] : &Bv[0][0])
                          + (wave & 1) * 64 * 32;   // wave-uniform base

    f32x4 aQ[4][2] = {}, aK[4][2] = {}, aV[2][4] = {};

#define QKV_STAGE(BUF, STEP)                                                  \
    do {                                                                      \
        _Pragma("unroll")                                                     \
        for (int g = 0; g < 4; ++g)                                           \
            gl2lds16(Sg + (STEP) * 32 + (size_t)g * 16 * D_MODEL,             \
                     LdB + (BUF) * 4096 + g * 512);                           \
    } while (0)

#define QKV_COMP(BUF)                                                         \
    do {                                                                      \
        bf16x8 xa[4], fq[2], fk[2], fv[2];                                    \
        _Pragma("unroll")                                                     \
        for (int i = 0; i < 4; ++i)                                           \
            xa[i] = *(const bf16x8*)(&Xs[(BUF)][0] + (wm + i * 16 + l16) * 32 + quad * 8); \
        _Pragma("unroll")                                                     \
        for (int j = 0; j < 2; ++j) {                                         \
            fq[j] = *(const bf16x8*)(&Bq[(BUF)][0] + (wn + j * 16 + l16) * 32 + quad * 8); \
            fk[j] = *(const bf16x8*)(&Bk[(BUF)][0] + (wn + j * 16 + l16) * 32 + quad * 8); \
            fv[j] = *(const bf16x8*)(&Bv[(BUF)][0] + (wn + j * 16 + l16) * 32 + quad * 8); \
        }                                                                     \
        _Pragma("unroll")                                                     \
        for (int i = 0; i < 4; ++i)                                           \
            _Pragma("unroll")                                                 \
            for (int j = 0; j < 2; ++j) {                                     \
                aQ[i][j] = __builtin_amdgcn_mfma_f32_16x16x32_bf16(xa[i], fq[j], aQ[i][j], 0, 0, 0); \
                aK[i][j] = __builtin_amdgcn_mfma_f32_16x16x32_bf16(xa[i], fk[j], aK[i][j], 0, 0, 0); \
                aV[j][i] = __builtin_amdgcn_mfma_f32_16x16x32_bf16(fv[j], xa[i], aV[j][i], 0, 0, 0); \
            }                                                                 \
    } while (0)

    QKV_STAGE(0, 0);
    __syncthreads();
    #pragma unroll 2
    for (int step = 0; step + 1 < 32; ++step) {      // 31 steady iterations
        const int cur = step & 1;
        QKV_STAGE(cur ^ 1, step + 1);   // issue loads FIRST (in flight over compute)
        QKV_COMP(cur);
        __syncthreads();                // vmcnt(0) drain AFTER full compute cover
    }
    QKV_COMP(1);                        // step 31 (buf 1), already staged
#undef QKV_STAGE
#undef QKV_COMP

    #pragma unroll
    for (int i = 0; i < 4; ++i)
        #pragma unroll
        for (int j = 0; j < 2; ++j)
            #pragma unroll
            for (int r = 0; r < 4; ++r) {
                const int mr = m0 + wm + i * 16 + quad * 4 + r;
                const int nc = n0 + wn + j * 16 + l16;
                Qo[(size_t)mr * D_MODEL + nc] = f2bf(aQ[i][j][r] * qscale);
                Ko[(size_t)mr * D_MODEL + nc] = f2bf(aK[i][j][r]);
                // V^T: row = weight-side of aV, col = x-side
                Vto[(size_t)(n0 + wn + j * 16 + quad * 4 + r) * MTOT
                    + (m0 + wm + i * 16 + l16)] = f2bf(aV[j][i][r]);
            }
}

// Output projection C_fp32[M,N] = A[M,K] @ W[N,K]^T, 128^2 tile, 512 thr,
// 2-PHASE pipelined: BK=64 double-buffered (16 steps), next-step loads
// issued before current-step compute, one barrier/step. XCD swizzle.
__global__ __launch_bounds__(512, 2) void gemm_o(
    const unsigned short* __restrict__ A,
    const unsigned short* __restrict__ W,
    float* __restrict__ C)
{
    const int id = blockIdx.x + 32 * blockIdx.y;
    const int sw = (id & 7) * 32 + (id >> 3);
    const int m0 = (sw & 31) * 128, n0 = (sw >> 5) * 128;

    __shared__ __align__(16) unsigned short As[2][2][128 * 32];  // [buf][s]
    __shared__ __align__(16) unsigned short Bs[2][2][128 * 32];  // 64 KiB

    const int t = threadIdx.x, wave = t >> 6, lane = t & 63;
    const int quad = lane >> 4, l16 = lane & 15;
    const int wm = (wave >> 2) * 64, wn = (wave & 3) * 32;

    // staging: wave w covers tile (w>>2), rows [(w&3)*32, +32) in 2 groups of 16
    const int stile = wave >> 2;
    const int srow  = (wave & 3) * 32 + (lane >> 2);
    const int schk  = (lane & 3) * 8;
    const unsigned short* Sg = (stile ? W : A)
        + (size_t)((stile ? n0 : m0) + srow) * D_MODEL + schk;
    unsigned short* LdB = (stile ? &Bs[0][0][0] : &As[0][0][0]) + (wave & 3) * 32 * 32;

    f32x4 acc[4][2] = {};

#define O_STAGE(BUF, STEP)                                                    \
    do {                                                                      \
        _Pragma("unroll")                                                     \
        for (int s = 0; s < 2; ++s)                                           \
            _Pragma("unroll")                                                 \
            for (int g = 0; g < 2; ++g)                                       \
                gl2lds16(Sg + (STEP) * 64 + s * 32 + (size_t)g * 16 * D_MODEL,\
                         LdB + (BUF) * 8192 + s * 4096 + g * 512);            \
    } while (0)

#define O_COMP(BUF)                                                           \
    do {                                                                      \
        _Pragma("unroll")                                                     \
        for (int s = 0; s < 2; ++s) {                                         \
            bf16x8 af[4], bfr[2];                                             \
            _Pragma("unroll")                                                 \
            for (int i = 0; i < 4; ++i)                                       \
                af[i] = *(const bf16x8*)(&As[(BUF)][s][0] + (wm + i * 16 + l16) * 32 + quad * 8); \
            _Pragma("unroll")                                                 \
            for (int j = 0; j < 2; ++j)                                       \
                bfr[j] = *(const bf16x8*)(&Bs[(BUF)][s][0] + (wn + j * 16 + l16) * 32 + quad * 8); \
            _Pragma("unroll")                                                 \
            for (int i = 0; i < 4; ++i)                                       \
                _Pragma("unroll")                                             \
                for (int j = 0; j < 2; ++j)                                   \
                    acc[i][j] = __builtin_amdgcn_mfma_f32_16x16x32_bf16(af[i], bfr[j], acc[i][j], 0, 0, 0); \
        }                                                                     \
    } while (0)

    O_STAGE(0, 0);
    __syncthreads();
    #pragma unroll 2
    for (int step = 0; step + 1 < 16; ++step) {      // 15 steady iterations
        const int cur = step & 1;
        O_STAGE(cur ^ 1, step + 1);
        O_COMP(cur);
        __syncthreads();
    }
    O_COMP(1);                                       // step 15
#undef O_STAGE
#undef O_COMP

    #pragma unroll
    for (int i = 0; i < 4; ++i)
        #pragma unroll
        for (int j = 0; j < 2; ++j)
            #pragma unroll
            for (int r = 0; r < 4; ++r)
                C[(size_t)(m0 + wm + i * 16 + quad * 4 + r) * D_MODEL
                  + n0 + wn + j * 16 + l16] = acc[i][j][r];
}

// Flash causal attention — round-0 verified kernel (64-q blocks, split-key
// waves, 2-barrier tile loop, 18 KiB LDS = 8-block/CU capacity for tail
// absorption) + 4-way split row-sum accumulators. Unchanged from round 3.
__global__ __launch_bounds__(256, 4) void attn_kernel(
    const unsigned short* __restrict__ Qm,
    const unsigned short* __restrict__ Km,
    const unsigned short* __restrict__ VtG,
    unsigned short* __restrict__ Om)
{
    const int bh = blockIdx.x;
    const int y  = blockIdx.y, g = y & 7, sl = y >> 3;
    const int qt = (sl == 0) ? 31 - g : (sl == 1) ? 16 + g : (sl == 2) ? 15 - g : g;
    const int h  = bh & 15;
    const int b  = bh >> 4;
    const int t     = threadIdx.x;
    const int wave  = t >> 6, lane = t & 63;
    const int qhalf = wave >> 1, khalf = wave & 1;
    const int l31   = lane & 31, h32 = lane >> 5;

    __shared__ __align__(16) unsigned short Ks[64 * 72];      // K tile [key][dk]
    __shared__ __align__(16) unsigned short Vt[64 * 72];      // V^T tile [dk][key]

    const size_t base = (size_t)b * SEQ * D_MODEL + (size_t)h * DKH;
    const unsigned short* Qh = Qm + base;
    const unsigned short* Kh = Km + base;
    const unsigned short* Vh = VtG + (size_t)h * DKH * MTOT + (size_t)b * SEQ;  // [dk][m]

    // Q B-frags (Q pre-scaled by log2e/8): B[n=q=l31][k=h32*8+j], 4 k-steps = dk 64
    const int qrow = qt * 64 + qhalf * 32 + l31;
    bf16x8 qf[4];
    #pragma unroll
    for (int ks = 0; ks < 4; ++ks)
        qf[ks] = *(const bf16x8*)(Qh + (size_t)qrow * D_MODEL + ks * 16 + h32 * 8);

    f32x16 accOT[2] = {};   // O^T partial: col=l31=q, row=(reg&3)+8*(reg>>2)+4*h32=dk (+32*db)
    float  la[4] = {0.f, 0.f, 0.f, 0.f};   // 4-way split row-sum partials

    const int srow = t >> 2, scol = (t & 3) * 16;
    const int kbase = khalf * 32;

    // prefetch K/V tile 0 into regs
    uint4 kr0, kr1, vr0, vr1;
    {
        const unsigned short* ks = Kh + (size_t)srow * D_MODEL + scol;
        kr0 = *(const uint4*)ks; kr1 = *(const uint4*)(ks + 8);
        const unsigned short* vs = Vh + (size_t)srow * MTOT + scol;
        vr0 = *(const uint4*)vs; vr1 = *(const uint4*)(vs + 8);
    }

    for (int kt = 0; kt <= qt; ++kt) {
        __syncthreads();   // prior iter's frag reads done
        *(uint4*)(Ks + srow * 72 + scol)     = kr0;
        *(uint4*)(Ks + srow * 72 + scol + 8) = kr1;
        *(uint4*)(Vt + srow * 72 + scol)     = vr0;
        *(uint4*)(Vt + srow * 72 + scol + 8) = vr1;
        __syncthreads();

        if (kt < qt) {     // prefetch next tile; overlaps compute below
            const unsigned short* ks = Kh + (size_t)((kt + 1) * 64 + srow) * D_MODEL + scol;
            kr0 = *(const uint4*)ks; kr1 = *(const uint4*)(ks + 8);
            const unsigned short* vs = Vh + (size_t)srow * MTOT + (kt + 1) * 64 + scol;
            vr0 = *(const uint4*)vs; vr1 = *(const uint4*)(vs + 8);
        }

        const bool diag = (kt == qt);
        if (diag && khalf > qhalf) continue;   // fully-masked quarter: skip

        // S^T = K Q^T : A=K rows (same LDS bytes as before, roles swapped)
        f32x16 sT = {};
        #pragma unroll
        for (int ks = 0; ks < 4; ++ks) {
            bf16x8 kf = *(const bf16x8*)(Ks + (kbase + l31) * 72 + ks * 16 + h32 * 8);
            sT = __builtin_amdgcn_mfma_f32_32x32x16_bf16(kf, qf[ks], sT, 0, 0, 0);
        }

        // p = exp2(s); mask on equal-half diag quarter: keep key(rloc) <= q(l31)
        const bool maskq = diag && (khalf == qhalf);
        float pv[16];
        #pragma unroll
        for (int reg = 0; reg < 16; ++reg) {
            const int rloc = (reg & 3) + 8 * (reg >> 2) + 4 * h32;   // key_local
            float v = sT[reg];
            if (maskq) v = (rloc <= l31) ? v : -1e30f;
            float p = exp2f(v);
            la[reg & 3] += p;
            pv[reg] = p;
        }
        // pack pairs (consecutive regs = consecutive keys) and half-wave exchange
        unsigned int pk[8], pr[8];
        #pragma unroll
        for (int i = 0; i < 8; ++i) pk[i] = pack2bf(pv[2 * i], pv[2 * i + 1]);
        #pragma unroll
        for (int i = 0; i < 8; ++i) pr[i] = __shfl_xor(pk[i], 32, 64);

        // O^T += V^T P^T : A = V^T rows (same bytes as before), B = P^T in regs
        #pragma unroll
        for (int ks2 = 0; ks2 < 2; ++ks2) {
            union { u32x4 u; bf16x8 b; } pf;
            pf.u[0] = h32 ? pr[4 * ks2 + 2] : pk[4 * ks2 + 0];
            pf.u[1] = h32 ? pr[4 * ks2 + 3] : pk[4 * ks2 + 1];
            pf.u[2] = h32 ? pk[4 * ks2 + 2] : pr[4 * ks2 + 0];
            pf.u[3] = h32 ? pk[4 * ks2 + 3] : pr[4 * ks2 + 1];
            #pragma unroll
            for (int db = 0; db < 2; ++db) {
                bf16x8 vf = *(const bf16x8*)(Vt + (db * 32 + l31) * 72 + kbase + ks2 * 16 + h32 * 8);
                accOT[db] = __builtin_amdgcn_mfma_f32_32x32x16_bf16(vf, pf.b, accOT[db], 0, 0, 0);
            }
        }
    }

    float l_s = (la[0] + la[1]) + (la[2] + la[3]);

    // ---- merge key halves (khalf 1 -> 0) through dead Ks/Vt ----
    __syncthreads();
    float* exO = (qhalf == 0) ? (float*)Ks : (float*)Vt;   // 64 lanes x 36 floats (32 O + l + pad)
    if (khalf == 1) {
        #pragma unroll
        for (int db = 0; db < 2; ++db)
            #pragma unroll
            for (int c = 0; c < 4; ++c) {
                float4 v = { accOT[db][c*4], accOT[db][c*4+1], accOT[db][c*4+2], accOT[db][c*4+3] };
                *(float4*)(exO + lane * 36 + db * 16 + c * 4) = v;
            }
        exO[lane * 36 + 32] = l_s;
    }
    __syncthreads();
    float inv = 0.f;
    if (khalf == 0) {
        #pragma unroll
        for (int db = 0; db < 2; ++db)
            #pragma unroll
            for (int c = 0; c < 4; ++c) {
                float4 v = *(const float4*)(exO + lane * 36 + db * 16 + c * 4);
                accOT[db][c*4]   += v.x; accOT[db][c*4+1] += v.y;
                accOT[db][c*4+2] += v.z; accOT[db][c*4+3] += v.w;
            }
        l_s += exO[lane * 36 + 32];
        l_s += __shfl_xor(l_s, 32, 64);   // other h32 half of the same q
        inv = 1.f / l_s;
    }
    __syncthreads();   // merge reads done; Ks free for the transpose tile

    // ---- transpose O^T -> [q][dk] bf16 tile in Ks, then coalesced store ----
    unsigned short* Ot = Ks;   // [64][68] u16
    if (khalf == 0) {
        const int row = qhalf * 32 + l31;
        #pragma unroll
        for (int db = 0; db < 2; ++db)
            #pragma unroll
            for (int c = 0; c < 4; ++c) {
                // dk pairs: (8c+4*h32, +1) and (+2, +3)
                unsigned int w0 = pack2bf(accOT[db][4*c]   * inv, accOT[db][4*c+1] * inv);
                unsigned int w1 = pack2bf(accOT[db][4*c+2] * inv, accOT[db][4*c+3] * inv);
                const int off = db * 32 + 8 * c + 4 * h32;
                *(unsigned int*)(Ot + row * 68 + off)     = w0;
                *(unsigned int*)(Ot + row * 68 + off + 2) = w1;
            }
    }
    __syncthreads();
    {
        const int row = t >> 2, col = (t & 3) * 16;
        uint4 o0 = *(const uint4*)(Ot + row * 68 + col);
        uint4 o1 = *(const uint4*)(Ot + row * 68 + col + 8);
        unsigned short* dst = Om + (size_t)(b * SEQ + qt * 64 + row) * D_MODEL + h * DKH + col;
        *(uint4*)(dst)     = o0;
        *(uint4*)(dst + 8) = o1;
    }
}

extern "C" void kernel_launch(void* const* d_in, const int* in_sizes, int n_in,
                              void* d_out, int out_size, void* d_ws, size_t ws_size,
                              hipStream_t stream) {
    const float* x   = (const float*)d_in[0];
    const float* w_q = (const float*)d_in[1];
    const float* w_k = (const float*)d_in[2];
    const float* w_v = (const float*)d_in[3];
    const float* w_o = (const float*)d_in[4];
    float* out = (float*)d_out;

    // ws (48 MB): xb 8 | weights 4x2 | Qb 8 | Kb 8 | VtG 8 | Ab 8
    unsigned short* xb  = (unsigned short*)d_ws;
    unsigned short* wqb = xb  + (size_t)MTOT * D_MODEL;
    unsigned short* wkb = wqb + (size_t)D_MODEL * D_MODEL;
    unsigned short* wvb = wkb + (size_t)D_MODEL * D_MODEL;
    unsigned short* wob = wvb + (size_t)D_MODEL * D_MODEL;
    unsigned short* Qb  = wob + (size_t)D_MODEL * D_MODEL;
    unsigned short* Kb  = Qb  + (size_t)MTOT * D_MODEL;
    unsigned short* VtG = Kb  + (size_t)MTOT * D_MODEL;   // V^T [1024][4096]
    unsigned short* Ab  = VtG + (size_t)MTOT * D_MODEL;

    cvt_all<<<dim3(2048 + 4 * 512), dim3(256), 0, stream>>>(
        x, w_q, w_k, w_v, w_o, xb, wqb, wkb, wvb, wob);
    // fused QKV projection, 2-phase pipelined; x-tile staged once for Q, K, V^T.
    // Q scale = (1/8) * log2(e) so attention can use exp2.
    qkv_fused<<<dim3(MTOT / 128, D_MODEL / 128), dim3(512), 0, stream>>>(
        xb, wqb, wkb, wvb, Qb, Kb, VtG, 0.125f * 1.44269504f);
    // balanced causal flash attention (round-0 verified structure)
    attn_kernel<<<dim3(BATCH * NHEADS, 32), dim3(256), 0, stream>>>(Qb, Kb, VtG, Ab);
    // output projection -> fp32 (2-phase pipelined)
    gemm_o<<<dim3(MTOT / 128, D_MODEL / 128), dim3(512), 0, stream>>>(Ab, wob, out);
}

// Round 5
// 163.942 us; speedup vs baseline: 1.1633x; 1.0291x over previous
//
#include <hip/hip_runtime.h>
#include <hip/hip_bf16.h>
#include <stdint.h>

#define D_MODEL 1024
#define NHEADS  16
#define DKH     64
#define BATCH   2
#define SEQ     2048
#define MTOT    (BATCH*SEQ)   // 4096

typedef __attribute__((ext_vector_type(8)))  short bf16x8;   // 8 bf16 = 4 VGPRs
typedef __attribute__((ext_vector_type(4)))  float f32x4;
typedef __attribute__((ext_vector_type(16))) float f32x16;
typedef __attribute__((ext_vector_type(4)))  unsigned int u32x4;

__device__ inline unsigned short f2bf(float f) {
    __hip_bfloat16 h = __float2bfloat16(f);
    return *reinterpret_cast<unsigned short*>(&h);
}
__device__ inline unsigned int pack2bf(float a, float b) {   // low=a, high=b (RNE)
    __hip_bfloat162 h = __float22bfloat162_rn(float2{a, b});
    return *reinterpret_cast<unsigned int*>(&h);
}

// async global->LDS, 16B per lane; LDS dest = wave-uniform base + lane*16 (m97/m104)
__device__ inline void gl2lds16(const unsigned short* g, unsigned short* l) {
    __builtin_amdgcn_global_load_lds(
        (const __attribute__((address_space(1))) void*)g,
        (__attribute__((address_space(3))) void*)l,
        16, 0, 0);
}

// One-shot fp32 -> bf16 conversion of x and the 4 weight matrices.
__global__ __launch_bounds__(256) void cvt_all(
    const float* __restrict__ x,  const float* __restrict__ wq,
    const float* __restrict__ wk, const float* __restrict__ wv,
    const float* __restrict__ wo,
    unsigned short* __restrict__ xb,  unsigned short* __restrict__ wqb,
    unsigned short* __restrict__ wkb, unsigned short* __restrict__ wvb,
    unsigned short* __restrict__ wob)
{
    int bid = blockIdx.x;
    const float* s; unsigned short* d; size_t base;
    if (bid < 2048) { s = x; d = xb; base = (size_t)bid * 2048; }
    else {
        int w  = (bid - 2048) >> 9;
        int wb = (bid - 2048) & 511;
        s = (w == 0) ? wq : (w == 1) ? wk : (w == 2) ? wv : wo;
        d = (w == 0) ? wqb : (w == 1) ? wkb : (w == 2) ? wvb : wob;
        base = (size_t)wb * 2048;
    }
    size_t i = base + (size_t)threadIdx.x * 8;
    float4 a = *(const float4*)(s + i);
    float4 b = *(const float4*)(s + i + 4);
    unsigned short t8[8] = {f2bf(a.x), f2bf(a.y), f2bf(a.z), f2bf(a.w),
                            f2bf(b.x), f2bf(b.y), f2bf(b.z), f2bf(b.w)};
    *(uint4*)(d + i) = *(uint4*)t8;
}

// Fused QKV projection, DEPTH-2 counted-vmcnt pipeline (T4, m201/m218 pattern):
// 3 LDS buffers; stage(t+2) issued each step; per-wave s_waitcnt vmcnt(8)
// waits only for the OLDEST batch (stage t, m135 in-order semantics) while
// stage(t+1)/(t+2) stay in flight across RAW s_barriers. Round-4's version
// used __syncthreads (= vmcnt(0)) -> at 1 block/CU every step ate a full
// HBM round-trip (3488 cyc/step vs 240 cyc MFMA). x-tile staged once for
// Q, K, V^T (in-block VSWAP). Bijective XCD swizzle.
// grid (32, 8) = 256 blocks, 512 thr (8 waves: wm=(w>>2)*64, wn=(w&3)*32).
__global__ __launch_bounds__(512, 2) void qkv_fused(
    const unsigned short* __restrict__ X,
    const unsigned short* __restrict__ Wq,
    const unsigned short* __restrict__ Wk,
    const unsigned short* __restrict__ Wv,
    unsigned short* __restrict__ Qo,
    unsigned short* __restrict__ Ko,
    unsigned short* __restrict__ Vto,
    float qscale)
{
    const int id = blockIdx.x + 32 * blockIdx.y;   // 256 blocks, 256%8==0
    const int sw = (id & 7) * 32 + (id >> 3);      // XCD c -> contiguous chunk
    const int m0 = (sw & 31) * 128;                // x-row tile
    const int n0 = (sw >> 5) * 128;                // weight-row tile

    // [buf 0..2][128 x 32 shorts] per tile; 4 tiles x 3 buf = 96 KiB
    __shared__ __align__(16) unsigned short Xs[3][128 * 32];
    __shared__ __align__(16) unsigned short Bq[3][128 * 32];
    __shared__ __align__(16) unsigned short Bk[3][128 * 32];
    __shared__ __align__(16) unsigned short Bv[3][128 * 32];

    const int t = threadIdx.x;
    const int wave = t >> 6, lane = t & 63;
    const int quad = lane >> 4, l16 = lane & 15;
    const int wm = (wave >> 2) * 64;
    const int wn = (wave & 3) * 32;

    // staging: wave w covers tile (w>>1), rows [(w&1)*64, +64) in 4 groups of 16
    const int stile = wave >> 1;
    const int srow  = (wave & 1) * 64 + (lane >> 2);
    const int schk  = (lane & 3) * 8;
    const unsigned short* gsrc = (stile == 0) ? X : (stile == 1) ? Wq :
                                 (stile == 2) ? Wk : Wv;
    const int grow0 = (stile == 0) ? m0 : n0;
    const unsigned short* Sg = gsrc + (size_t)(grow0 + srow) * D_MODEL + schk;
    unsigned short* LdB = ((stile == 0) ? &Xs[0][0] : (stile == 1) ? &Bq[0][0] :
                           (stile == 2) ? &Bk[0][0] : &Bv[0][0])
                          + (wave & 1) * 64 * 32;   // wave-uniform base

    f32x4 aQ[4][2] = {}, aK[4][2] = {}, aV[2][4] = {};

#define QKV_STAGE(BUF, STEP)                                                  \
    do {                                                                      \
        _Pragma("unroll")                                                     \
        for (int g = 0; g < 4; ++g)                                           \
            gl2lds16(Sg + (STEP) * 32 + (size_t)g * 16 * D_MODEL,             \
                     LdB + (BUF) * 4096 + g * 512);                           \
    } while (0)

#define QKV_COMP(BUF)                                                         \
    do {                                                                      \
        bf16x8 xa[4], fq[2], fk[2], fv[2];                                    \
        _Pragma("unroll")                                                     \
        for (int i = 0; i < 4; ++i)                                           \
            xa[i] = *(const bf16x8*)(&Xs[(BUF)][0] + (wm + i * 16 + l16) * 32 + quad * 8); \
        _Pragma("unroll")                                                     \
        for (int j = 0; j < 2; ++j) {                                         \
            fq[j] = *(const bf16x8*)(&Bq[(BUF)][0] + (wn + j * 16 + l16) * 32 + quad * 8); \
            fk[j] = *(const bf16x8*)(&Bk[(BUF)][0] + (wn + j * 16 + l16) * 32 + quad * 8); \
            fv[j] = *(const bf16x8*)(&Bv[(BUF)][0] + (wn + j * 16 + l16) * 32 + quad * 8); \
        }                                                                     \
        _Pragma("unroll")                                                     \
        for (int i = 0; i < 4; ++i)                                           \
            _Pragma("unroll")                                                 \
            for (int j = 0; j < 2; ++j) {                                     \
                aQ[i][j] = __builtin_amdgcn_mfma_f32_16x16x32_bf16(xa[i], fq[j], aQ[i][j], 0, 0, 0); \
                aK[i][j] = __builtin_amdgcn_mfma_f32_16x16x32_bf16(xa[i], fk[j], aK[i][j], 0, 0, 0); \
                aV[j][i] = __builtin_amdgcn_mfma_f32_16x16x32_bf16(fv[j], xa[i], aV[j][i], 0, 0, 0); \
            }                                                                 \
    } while (0)

    QKV_STAGE(0, 0);          // 4 loads in flight
    QKV_STAGE(1, 1);          // 8 loads in flight
    for (int step = 0; step < 32; ++step) {
        __builtin_amdgcn_s_barrier();            // A: compute(step-1) done everywhere
        const int nxt = step + 2;                //    -> B[(step+2)%3] is free (WAR)
        if (nxt < 32) QKV_STAGE(nxt % 3, nxt);   // 12 in flight
        if (step < 30)      asm volatile("s_waitcnt vmcnt(8)" ::: "memory");  // stage(step) landed
        else if (step < 31) asm volatile("s_waitcnt vmcnt(4)" ::: "memory");
        else                asm volatile("s_waitcnt vmcnt(0)" ::: "memory");
        __builtin_amdgcn_s_barrier();            // B: everyone's stage(step) visible
        __builtin_amdgcn_sched_barrier(0);
        QKV_COMP(step % 3);
    }
#undef QKV_STAGE
#undef QKV_COMP

    #pragma unroll
    for (int i = 0; i < 4; ++i)
        #pragma unroll
        for (int j = 0; j < 2; ++j)
            #pragma unroll
            for (int r = 0; r < 4; ++r) {
                const int mr = m0 + wm + i * 16 + quad * 4 + r;
                const int nc = n0 + wn + j * 16 + l16;
                Qo[(size_t)mr * D_MODEL + nc] = f2bf(aQ[i][j][r] * qscale);
                Ko[(size_t)mr * D_MODEL + nc] = f2bf(aK[i][j][r]);
                // V^T: row = weight-side of aV, col = x-side
                Vto[(size_t)(n0 + wn + j * 16 + quad * 4 + r) * MTOT
                    + (m0 + wm + i * 16 + l16)] = f2bf(aV[j][i][r]);
            }
}

// Output projection C_fp32[M,N] = A[M,K] @ W[N,K]^T, 128^2 tile, 512 thr,
// DEPTH-2 counted-vmcnt pipeline: BK=32, 3 LDS buffers (48 KiB), 2 loads/wave
// per stage batch -> vmcnt(4) steady state, raw barriers. XCD swizzle.
__global__ __launch_bounds__(512, 2) void gemm_o(
    const unsigned short* __restrict__ A,
    const unsigned short* __restrict__ W,
    float* __restrict__ C)
{
    const int id = blockIdx.x + 32 * blockIdx.y;
    const int sw = (id & 7) * 32 + (id >> 3);
    const int m0 = (sw & 31) * 128, n0 = (sw >> 5) * 128;

    __shared__ __align__(16) unsigned short As[3][128 * 32];
    __shared__ __align__(16) unsigned short Bs[3][128 * 32];   // 48 KiB

    const int t = threadIdx.x, wave = t >> 6, lane = t & 63;
    const int quad = lane >> 4, l16 = lane & 15;
    const int wm = (wave >> 2) * 64, wn = (wave & 3) * 32;

    // staging: wave w covers tile (w>>2), rows [(w&3)*32, +32) in 2 groups of 16
    const int stile = wave >> 2;
    const int srow  = (wave & 3) * 32 + (lane >> 2);
    const int schk  = (lane & 3) * 8;
    const unsigned short* Sg = (stile ? W : A)
        + (size_t)((stile ? n0 : m0) + srow) * D_MODEL + schk;
    unsigned short* LdB = (stile ? &Bs[0][0] : &As[0][0]) + (wave & 3) * 32 * 32;

    f32x4 acc[4][2] = {};

#define O_STAGE(BUF, STEP)                                                    \
    do {                                                                      \
        _Pragma("unroll")                                                     \
        for (int g = 0; g < 2; ++g)                                           \
            gl2lds16(Sg + (STEP) * 32 + (size_t)g * 16 * D_MODEL,             \
                     LdB + (BUF) * 4096 + g * 512);                           \
    } while (0)

#define O_COMP(BUF)                                                           \
    do {                                                                      \
        bf16x8 af[4], bfr[2];                                                 \
        _Pragma("unroll")                                                     \
        for (int i = 0; i < 4; ++i)                                           \
            af[i] = *(const bf16x8*)(&As[(BUF)][0] + (wm + i * 16 + l16) * 32 + quad * 8); \
        _Pragma("unroll")                                                     \
        for (int j = 0; j < 2; ++j)                                           \
            bfr[j] = *(const bf16x8*)(&Bs[(BUF)][0] + (wn + j * 16 + l16) * 32 + quad * 8); \
        _Pragma("unroll")                                                     \
        for (int i = 0; i < 4; ++i)                                           \
            _Pragma("unroll")                                                 \
            for (int j = 0; j < 2; ++j)                                       \
                acc[i][j] = __builtin_amdgcn_mfma_f32_16x16x32_bf16(af[i], bfr[j], acc[i][j], 0, 0, 0); \
    } while (0)

    O_STAGE(0, 0);
    O_STAGE(1, 1);
    for (int step = 0; step < 32; ++step) {
        __builtin_amdgcn_s_barrier();            // A: WAR guard
        const int nxt = step + 2;
        if (nxt < 32) O_STAGE(nxt % 3, nxt);
        if (step < 30)      asm volatile("s_waitcnt vmcnt(4)" ::: "memory");
        else if (step < 31) asm volatile("s_waitcnt vmcnt(2)" ::: "memory");
        else                asm volatile("s_waitcnt vmcnt(0)" ::: "memory");
        __builtin_amdgcn_s_barrier();            // B: stage(step) visible
        __builtin_amdgcn_sched_barrier(0);
        O_COMP(step % 3);
    }
#undef O_STAGE
#undef O_COMP

    #pragma unroll
    for (int i = 0; i < 4; ++i)
        #pragma unroll
        for (int j = 0; j < 2; ++j)
            #pragma unroll
            for (int r = 0; r < 4; ++r)
                C[(size_t)(m0 + wm + i * 16 + quad * 4 + r) * D_MODEL
                  + n0 + wn + j * 16 + l16] = acc[i][j][r];
}

// Flash causal attention — round-0 verified kernel (64-q blocks, split-key
// waves, 2-barrier tile loop, 18 KiB LDS = 8-block/CU capacity for tail
// absorption) + 4-way split row-sum accumulators. Unchanged.
__global__ __launch_bounds__(256, 4) void attn_kernel(
    const unsigned short* __restrict__ Qm,
    const unsigned short* __restrict__ Km,
    const unsigned short* __restrict__ VtG,
    unsigned short* __restrict__ Om)
{
    const int bh = blockIdx.x;
    const int y  = blockIdx.y, g = y & 7, sl = y >> 3;
    const int qt = (sl == 0) ? 31 - g : (sl == 1) ? 16 + g : (sl == 2) ? 15 - g : g;
    const int h  = bh & 15;
    const int b  = bh >> 4;
    const int t     = threadIdx.x;
    const int wave  = t >> 6, lane = t & 63;
    const int qhalf = wave >> 1, khalf = wave & 1;
    const int l31   = lane & 31, h32 = lane >> 5;

    __shared__ __align__(16) unsigned short Ks[64 * 72];      // K tile [key][dk]
    __shared__ __align__(16) unsigned short Vt[64 * 72];      // V^T tile [dk][key]

    const size_t base = (size_t)b * SEQ * D_MODEL + (size_t)h * DKH;
    const unsigned short* Qh = Qm + base;
    const unsigned short* Kh = Km + base;
    const unsigned short* Vh = VtG + (size_t)h * DKH * MTOT + (size_t)b * SEQ;  // [dk][m]

    // Q B-frags (Q pre-scaled by log2e/8): B[n=q=l31][k=h32*8+j], 4 k-steps = dk 64
    const int qrow = qt * 64 + qhalf * 32 + l31;
    bf16x8 qf[4];
    #pragma unroll
    for (int ks = 0; ks < 4; ++ks)
        qf[ks] = *(const bf16x8*)(Qh + (size_t)qrow * D_MODEL + ks * 16 + h32 * 8);

    f32x16 accOT[2] = {};   // O^T partial: col=l31=q, row=(reg&3)+8*(reg>>2)+4*h32=dk (+32*db)
    float  la[4] = {0.f, 0.f, 0.f, 0.f};   // 4-way split row-sum partials

    const int srow = t >> 2, scol = (t & 3) * 16;
    const int kbase = khalf * 32;

    // prefetch K/V tile 0 into regs
    uint4 kr0, kr1, vr0, vr1;
    {
        const unsigned short* ks = Kh + (size_t)srow * D_MODEL + scol;
        kr0 = *(const uint4*)ks; kr1 = *(const uint4*)(ks + 8);
        const unsigned short* vs = Vh + (size_t)srow * MTOT + scol;
        vr0 = *(const uint4*)vs; vr1 = *(const uint4*)(vs + 8);
    }

    for (int kt = 0; kt <= qt; ++kt) {
        __syncthreads();   // prior iter's frag reads done
        *(uint4*)(Ks + srow * 72 + scol)     = kr0;
        *(uint4*)(Ks + srow * 72 + scol + 8) = kr1;
        *(uint4*)(Vt + srow * 72 + scol)     = vr0;
        *(uint4*)(Vt + srow * 72 + scol + 8) = vr1;
        __syncthreads();

        if (kt < qt) {     // prefetch next tile; overlaps compute below
            const unsigned short* ks = Kh + (size_t)((kt + 1) * 64 + srow) * D_MODEL + scol;
            kr0 = *(const uint4*)ks; kr1 = *(const uint4*)(ks + 8);
            const unsigned short* vs = Vh + (size_t)srow * MTOT + (kt + 1) * 64 + scol;
            vr0 = *(const uint4*)vs; vr1 = *(const uint4*)(vs + 8);
        }

        const bool diag = (kt == qt);
        if (diag && khalf > qhalf) continue;   // fully-masked quarter: skip

        // S^T = K Q^T : A=K rows (same LDS bytes as before, roles swapped)
        f32x16 sT = {};
        #pragma unroll
        for (int ks = 0; ks < 4; ++ks) {
            bf16x8 kf = *(const bf16x8*)(Ks + (kbase + l31) * 72 + ks * 16 + h32 * 8);
            sT = __builtin_amdgcn_mfma_f32_32x32x16_bf16(kf, qf[ks], sT, 0, 0, 0);
        }

        // p = exp2(s); mask on equal-half diag quarter: keep key(rloc) <= q(l31)
        const bool maskq = diag && (khalf == qhalf);
        float pv[16];
        #pragma unroll
        for (int reg = 0; reg < 16; ++reg) {
            const int rloc = (reg & 3) + 8 * (reg >> 2) + 4 * h32;   // key_local
            float v = sT[reg];
            if (maskq) v = (rloc <= l31) ? v : -1e30f;
            float p = exp2f(v);
            la[reg & 3] += p;
            pv[reg] = p;
        }
        // pack pairs (consecutive regs = consecutive keys) and half-wave exchange
        unsigned int pk[8], pr[8];
        #pragma unroll
        for (int i = 0; i < 8; ++i) pk[i] = pack2bf(pv[2 * i], pv[2 * i + 1]);
        #pragma unroll
        for (int i = 0; i < 8; ++i) pr[i] = __shfl_xor(pk[i], 32, 64);

        // O^T += V^T P^T : A = V^T rows (same bytes as before), B = P^T in regs
        #pragma unroll
        for (int ks2 = 0; ks2 < 2; ++ks2) {
            union { u32x4 u; bf16x8 b; } pf;
            pf.u[0] = h32 ? pr[4 * ks2 + 2] : pk[4 * ks2 + 0];
            pf.u[1] = h32 ? pr[4 * ks2 + 3] : pk[4 * ks2 + 1];
            pf.u[2] = h32 ? pk[4 * ks2 + 2] : pr[4 * ks2 + 0];
            pf.u[3] = h32 ? pk[4 * ks2 + 3] : pr[4 * ks2 + 1];
            #pragma unroll
            for (int db = 0; db < 2; ++db) {
                bf16x8 vf = *(const bf16x8*)(Vt + (db * 32 + l31) * 72 + kbase + ks2 * 16 + h32 * 8);
                accOT[db] = __builtin_amdgcn_mfma_f32_32x32x16_bf16(vf, pf.b, accOT[db], 0, 0, 0);
            }
        }
    }

    float l_s = (la[0] + la[1]) + (la[2] + la[3]);

    // ---- merge key halves (khalf 1 -> 0) through dead Ks/Vt ----
    __syncthreads();
    float* exO = (qhalf == 0) ? (float*)Ks : (float*)Vt;   // 64 lanes x 36 floats (32 O + l + pad)
    if (khalf == 1) {
        #pragma unroll
        for (int db = 0; db < 2; ++db)
            #pragma unroll
            for (int c = 0; c < 4; ++c) {
                float4 v = { accOT[db][c*4], accOT[db][c*4+1], accOT[db][c*4+2], accOT[db][c*4+3] };
                *(float4*)(exO + lane * 36 + db * 16 + c * 4) = v;
            }
        exO[lane * 36 + 32] = l_s;
    }
    __syncthreads();
    float inv = 0.f;
    if (khalf == 0) {
        #pragma unroll
        for (int db = 0; db < 2; ++db)
            #pragma unroll
            for (int c = 0; c < 4; ++c) {
                float4 v = *(const float4*)(exO + lane * 36 + db * 16 + c * 4);
                accOT[db][c*4]   += v.x; accOT[db][c*4+1] += v.y;
                accOT[db][c*4+2] += v.z; accOT[db][c*4+3] += v.w;
            }
        l_s += exO[lane * 36 + 32];
        l_s += __shfl_xor(l_s, 32, 64);   // other h32 half of the same q
        inv = 1.f / l_s;
    }
    __syncthreads();   // merge reads done; Ks free for the transpose tile

    // ---- transpose O^T -> [q][dk] bf16 tile in Ks, then coalesced store ----
    unsigned short* Ot = Ks;   // [64][68] u16
    if (khalf == 0) {
        const int row = qhalf * 32 + l31;
        #pragma unroll
        for (int db = 0; db < 2; ++db)
            #pragma unroll
            for (int c = 0; c < 4; ++c) {
                // dk pairs: (8c+4*h32, +1) and (+2, +3)
                unsigned int w0 = pack2bf(accOT[db][4*c]   * inv, accOT[db][4*c+1] * inv);
                unsigned int w1 = pack2bf(accOT[db][4*c+2] * inv, accOT[db][4*c+3] * inv);
                const int off = db * 32 + 8 * c + 4 * h32;
                *(unsigned int*)(Ot + row * 68 + off)     = w0;
                *(unsigned int*)(Ot + row * 68 + off + 2) = w1;
            }
    }
    __syncthreads();
    {
        const int row = t >> 2, col = (t & 3) * 16;
        uint4 o0 = *(const uint4*)(Ot + row * 68 + col);
        uint4 o1 = *(const uint4*)(Ot + row * 68 + col + 8);
        unsigned short* dst = Om + (size_t)(b * SEQ + qt * 64 + row) * D_MODEL + h * DKH + col;
        *(uint4*)(dst)     = o0;
        *(uint4*)(dst + 8) = o1;
    }
}

extern "C" void kernel_launch(void* const* d_in, const int* in_sizes, int n_in,
                              void* d_out, int out_size, void* d_ws, size_t ws_size,
                              hipStream_t stream) {
    const float* x   = (const float*)d_in[0];
    const float* w_q = (const float*)d_in[1];
    const float* w_k = (const float*)d_in[2];
    const float* w_v = (const float*)d_in[3];
    const float* w_o = (const float*)d_in[4];
    float* out = (float*)d_out;

    // ws (48 MB): xb 8 | weights 4x2 | Qb 8 | Kb 8 | VtG 8 | Ab 8
    unsigned short* xb  = (unsigned short*)d_ws;
    unsigned short* wqb = xb  + (size_t)MTOT * D_MODEL;
    unsigned short* wkb = wqb + (size_t)D_MODEL * D_MODEL;
    unsigned short* wvb = wkb + (size_t)D_MODEL * D_MODEL;
    unsigned short* wob = wvb + (size_t)D_MODEL * D_MODEL;
    unsigned short* Qb  = wob + (size_t)D_MODEL * D_MODEL;
    unsigned short* Kb  = Qb  + (size_t)MTOT * D_MODEL;
    unsigned short* VtG = Kb  + (size_t)MTOT * D_MODEL;   // V^T [1024][4096]
    unsigned short* Ab  = VtG + (size_t)MTOT * D_MODEL;

    cvt_all<<<dim3(2048 + 4 * 512), dim3(256), 0, stream>>>(
        x, w_q, w_k, w_v, w_o, xb, wqb, wkb, wvb, wob);
    // fused QKV projection, depth-2 counted-vmcnt pipeline; x staged once.
    // Q scale = (1/8) * log2(e) so attention can use exp2.
    qkv_fused<<<dim3(MTOT / 128, D_MODEL / 128), dim3(512), 0, stream>>>(
        xb, wqb, wkb, wvb, Qb, Kb, VtG, 0.125f * 1.44269504f);
    // balanced causal flash attention (round-0 verified structure)
    attn_kernel<<<dim3(BATCH * NHEADS, 32), dim3(256), 0, stream>>>(Qb, Kb, VtG, Ab);
    // output projection -> fp32 (depth-2 counted-vmcnt pipeline)
    gemm_o<<<dim3(MTOT / 128, D_MODEL / 128), dim3(512), 0, stream>>>(Ab, wob, out);
}